// Round 11
// baseline (456.683 us; speedup 1.0000x reference)
//
#include <hip/hip_runtime.h>

// ---------------------------------------------------------------------------
// Hetero GraphSAGE (user<->movie). Bucketed CSR build, bf16 gather tables,
// MFMA movie projection, register-tiled SAGE linear, layer-2 z-trick.
// ---------------------------------------------------------------------------

constexpr int NU = 100000;   // users
constexpr int NM = 50000;    // movies
constexpr int NE = 4000000;  // edges
constexpr int FU = 24;       // user feat
constexpr int FM = 404;      // movie feat
constexpr int HD = 64;       // hidden

constexpr int BSH = 8;                       // bucket = 256 node ids
constexpr int MBK = (NM + 255) >> BSH;       // 196 movie buckets
constexpr int UBK = (NU + 255) >> BSH;       // 391 user buckets
constexpr int NBK = MBK + UBK;               // 587
constexpr int EPB = 16384;                   // edges per passA block (1024 thr x 16)

static inline size_t alignup(size_t x) { return (x + 255) & ~size_t(255); }

__device__ __forceinline__ float bf2f(unsigned short h) {
  return __uint_as_float(((unsigned int)h) << 16);
}
__device__ __forceinline__ unsigned short f2bf(float f) {
  unsigned int u = __float_as_uint(f);
  u = (u + 0x7FFFu + ((u >> 16) & 1u)) >> 16;   // RNE
  return (unsigned short)u;
}
__device__ __forceinline__ float2 unpk(unsigned u) {
  return make_float2(__uint_as_float(u << 16), __uint_as_float(u & 0xFFFF0000u));
}

using bf16x8 = __attribute__((ext_vector_type(8))) short;   // 8 bf16 = 4 VGPRs
using f32x4  = __attribute__((ext_vector_type(4))) float;   // MFMA C/D frag

// ---------------- CSR build ----------------

__global__ __launch_bounds__(256) void histB_kernel(const int* __restrict__ src,
                                                    const int* __restrict__ dst,
                                                    int* __restrict__ bh) {
  __shared__ int h[NBK];
  for (int i = threadIdx.x; i < NBK; i += 256) h[i] = 0;
  __syncthreads();
  int idx = blockIdx.x * 256 + threadIdx.x;
  int stride = gridDim.x * 256;
  for (int i = idx; i < NE; i += stride) {
    atomicAdd(&h[dst[i] >> BSH], 1);
    atomicAdd(&h[MBK + (src[i] >> BSH)], 1);
  }
  __syncthreads();
  for (int i = threadIdx.x; i < NBK; i += 256) {
    int c = h[i];
    if (c) atomicAdd(&bh[i], c);
  }
}

__global__ __launch_bounds__(1024) void scanB_kernel(const int* __restrict__ bh,
                                                     int* __restrict__ bbase_m,
                                                     int* __restrict__ bbase_u,
                                                     int* __restrict__ bcur_m,
                                                     int* __restrict__ bcur_u) {
  __shared__ int tmp[1024];
  int t = threadIdx.x;
  int vm = (t < MBK) ? bh[t] : 0;
  tmp[t] = vm;
  __syncthreads();
  for (int off = 1; off < 1024; off <<= 1) {
    int v = (t >= off) ? tmp[t - off] : 0;
    __syncthreads();
    tmp[t] += v;
    __syncthreads();
  }
  if (t < MBK) {
    int e = tmp[t] - vm;
    bbase_m[t] = e; bcur_m[t] = e;
    if (t == MBK - 1) bbase_m[MBK] = tmp[t];
  }
  __syncthreads();
  int vu = (t < UBK) ? bh[MBK + t] : 0;
  tmp[t] = vu;
  __syncthreads();
  for (int off = 1; off < 1024; off <<= 1) {
    int v = (t >= off) ? tmp[t - off] : 0;
    __syncthreads();
    tmp[t] += v;
    __syncthreads();
  }
  if (t < UBK) {
    int e = tmp[t] - vu;
    bbase_u[t] = e; bcur_u[t] = e;
    if (t == UBK - 1) bbase_u[UBK] = tmp[t];
  }
}

// Pass A: scatter edges into bucket-ordered staging. 16 items/thread;
// ranks packed (rm | ru<<16, both < EPB=16384) to curb VGPR pressure.
__global__ __launch_bounds__(1024) void passA_kernel(
    const int* __restrict__ src, const int* __restrict__ dst,
    int* __restrict__ bcur_m, int* __restrict__ bcur_u,
    unsigned* __restrict__ stage_m, unsigned* __restrict__ stage_u) {
  __shared__ int hB[NBK];
  int t = threadIdx.x;
  for (int i = t; i < NBK; i += 1024) hB[i] = 0;
  __syncthreads();
  int e0 = blockIdx.x * EPB + t;
  int sv[16], dv[16];
  unsigned rr[16];
#pragma unroll
  for (int k = 0; k < 16; ++k) {
    int e = e0 + k * 1024;
    if (e < NE) {
      int s = src[e], d = dst[e];
      sv[k] = s; dv[k] = d;
      unsigned rm = (unsigned)atomicAdd(&hB[d >> BSH], 1);
      unsigned ru = (unsigned)atomicAdd(&hB[MBK + (s >> BSH)], 1);
      rr[k] = rm | (ru << 16);
    } else {
      sv[k] = -1;
    }
  }
  __syncthreads();
  for (int i = t; i < NBK; i += 1024) {
    int c = hB[i];
    int base = 0;
    if (c) base = (i < MBK) ? atomicAdd(&bcur_m[i], c) : atomicAdd(&bcur_u[i - MBK], c);
    hB[i] = base;
  }
  __syncthreads();
#pragma unroll
  for (int k = 0; k < 16; ++k) {
    if (sv[k] >= 0) {
      int s = sv[k], d = dv[k];
      stage_m[hB[d >> BSH] + (rr[k] & 0xFFFFu)] = ((unsigned)(d & 255) << 24) | (unsigned)s;
      stage_u[hB[MBK + (s >> BSH)] + (rr[k] >> 16)] = ((unsigned)(s & 255) << 24) | (unsigned)d;
    }
  }
}

__global__ __launch_bounds__(1024) void passB_kernel(
    const int* __restrict__ bbase_m, const int* __restrict__ bbase_u,
    const unsigned* __restrict__ stage_m, const unsigned* __restrict__ stage_u,
    int* __restrict__ csr_m, int* __restrict__ csr_u,
    int* __restrict__ rp_m, int* __restrict__ rp_u) {
  __shared__ int cnt[256];
  __shared__ int sc[256];
  int b = blockIdx.x;
  const unsigned* stage; int* csr; int* rp; int idbase, ntot, bb, be;
  if (b < MBK) {
    stage = stage_m; csr = csr_m; rp = rp_m;
    idbase = b << BSH; ntot = NM;
    bb = bbase_m[b]; be = bbase_m[b + 1];
  } else {
    int c = b - MBK;
    stage = stage_u; csr = csr_u; rp = rp_u;
    idbase = c << BSH; ntot = NU;
    bb = bbase_u[c]; be = bbase_u[c + 1];
  }
  int nloc = min(256, ntot - idbase);
  int t = threadIdx.x;
  if (t < 256) cnt[t] = 0;
  __syncthreads();
  for (int j = bb + t; j < be; j += 1024) atomicAdd(&cnt[stage[j] >> 24], 1);
  __syncthreads();
  int c0 = (t < 256) ? cnt[t] : 0;
  if (t < 256) sc[t] = c0;
  __syncthreads();
  for (int off = 1; off < 256; off <<= 1) {
    int v = 0;
    if (t < 256 && t >= off) v = sc[t - off];
    __syncthreads();
    if (t < 256) sc[t] += v;
    __syncthreads();
  }
  if (t < nloc) {
    int e = bb + sc[t] - c0;
    rp[idbase + t] = e;
    cnt[t] = e;                     // reuse as cursor
  }
  if (t == 0 && idbase + nloc == ntot) rp[ntot] = be;
  __syncthreads();
  for (int j = bb + t; j < be; j += 1024) {
    unsigned e = stage[j];
    int pos = atomicAdd(&cnt[e >> 24], 1);
    csr[pos] = (int)(e & 0xFFFFFFu);
  }
}

// ---------------- input projections (write bf16 tables) ----------------

__global__ void proj_user_kernel(const float* __restrict__ xu, const float* __restrict__ Wu,
                                 const float* __restrict__ bu, unsigned short* __restrict__ hu) {
  __shared__ float Wt[FU][HD + 1];
  __shared__ float Xl[16][FU];
  int t = threadIdx.x;
  int lane = t & 63, wg = t >> 6;
  int row0 = blockIdx.x * 16;
  for (int h = wg; h < HD; h += 4)
    if (lane < FU) Wt[lane][h] = Wu[h * FU + lane];
  for (int r = wg; r < 16; r += 4)
    if (lane < FU) Xl[r][lane] = xu[(row0 + r) * FU + lane];
  __syncthreads();
  float b = bu[lane];
  float acc[4] = {0.f, 0.f, 0.f, 0.f};
  for (int k = 0; k < FU; ++k) {
    float w = Wt[k][lane];
#pragma unroll
    for (int j = 0; j < 4; ++j) acc[j] += Xl[wg * 4 + j][k] * w;
  }
#pragma unroll
  for (int j = 0; j < 4; ++j)
    hu[(row0 + wg * 4 + j) * HD + lane] = f2bf(acc[j] + b);
}

// W_movie fp32 -> bf16 (once per launch)
__global__ void convW_kernel(const float* __restrict__ W, unsigned short* __restrict__ Wb,
                             int n) {
  int i = blockIdx.x * 256 + threadIdx.x;
  if (i < n) Wb[i] = f2bf(W[i]);
}

// Movie projection via MFMA (round-10 config, measured off top-5).
__global__ __launch_bounds__(256) void proj_movie_kernel(
    const float* __restrict__ xm, const unsigned short* __restrict__ Wb,
    const float* __restrict__ bm, unsigned short* __restrict__ hm) {
  __shared__ unsigned short Xs[64][72];
  __shared__ unsigned short Ws[64][72];
  int t = threadIdx.x;
  int lane = t & 63, wid = t >> 6;
  int row0 = blockIdx.x * 64;
  int r0 = wid * 16;
  f32x4 acc[4];
#pragma unroll
  for (int nt = 0; nt < 4; ++nt) acc[nt] = (f32x4){0.f, 0.f, 0.f, 0.f};

  for (int k0 = 0; k0 < 448; k0 += 64) {
    int kc = min(64, FM - k0);
    __syncthreads();
    for (int i = t; i < 1024; i += 256) {
      int r = i >> 4, c4 = i & 15;
      float4 v = make_float4(0.f, 0.f, 0.f, 0.f);
      if (c4 * 4 < kc && row0 + r < NM)
        v = *(const float4*)(xm + (size_t)(row0 + r) * FM + k0 + c4 * 4);
      ushort4 o;
      o.x = f2bf(v.x); o.y = f2bf(v.y); o.z = f2bf(v.z); o.w = f2bf(v.w);
      *(ushort4*)&Xs[r][c4 * 4] = o;
    }
    for (int i = t; i < 1024; i += 256) {
      int h = i >> 4, c4 = i & 15;
      uint2 v = make_uint2(0u, 0u);
      if (c4 * 4 < kc)
        v = *(const uint2*)(Wb + (size_t)h * FM + k0 + c4 * 4);
      *(uint2*)&Ws[h][c4 * 4] = v;
    }
    __syncthreads();
#pragma unroll
    for (int kk = 0; kk < 64; kk += 32) {
      bf16x8 a = *(const bf16x8*)&Xs[r0 + (lane & 15)][kk + (lane >> 4) * 8];
#pragma unroll
      for (int nt = 0; nt < 4; ++nt) {
        bf16x8 b = *(const bf16x8*)&Ws[nt * 16 + (lane & 15)][kk + (lane >> 4) * 8];
        acc[nt] = __builtin_amdgcn_mfma_f32_16x16x32_bf16(a, b, acc[nt], 0, 0, 0);
      }
    }
  }
  int col = lane & 15;
  int rbase = r0 + (lane >> 4) * 4;
#pragma unroll
  for (int nt = 0; nt < 4; ++nt) {
    float b = bm[nt * 16 + col];
#pragma unroll
    for (int j = 0; j < 4; ++j) {
      int row = row0 + rbase + j;
      if (row < NM)
        hm[(size_t)row * HD + nt * 16 + col] = f2bf(acc[nt][j] + b);
    }
  }
}

// ---------------- mean aggregation: 4 neighbors/wave, 16-deep unroll ------

__global__ __launch_bounds__(256) void agg_mean_kernel(
    const unsigned short* __restrict__ table, const int* __restrict__ rp,
    const int* __restrict__ csr, float* __restrict__ out, int n) {
  int wid = threadIdx.x >> 6;
  int lane = threadIdx.x & 63;
  int row = blockIdx.x * 4 + wid;
  if (row >= n) return;
  int beg = rp[row], end = rp[row + 1];
  int g = lane >> 4;        // neighbor slot 0..3
  int fq = lane & 15;       // feature quad
  float a0 = 0.f, a1 = 0.f, a2 = 0.f, a3 = 0.f;
  int i = beg;
  for (; i + 16 <= end; i += 16) {
    int n0 = csr[i + g];
    int n1 = csr[i + 4 + g];
    int n2 = csr[i + 8 + g];
    int n3 = csr[i + 12 + g];
    uint2 v0 = *(const uint2*)(table + (size_t)n0 * HD + fq * 4);
    uint2 v1 = *(const uint2*)(table + (size_t)n1 * HD + fq * 4);
    uint2 v2 = *(const uint2*)(table + (size_t)n2 * HD + fq * 4);
    uint2 v3 = *(const uint2*)(table + (size_t)n3 * HD + fq * 4);
    float2 p0 = unpk(v0.x), p1 = unpk(v0.y);
    float2 q0 = unpk(v1.x), q1 = unpk(v1.y);
    float2 r0 = unpk(v2.x), r1 = unpk(v2.y);
    float2 s0 = unpk(v3.x), s1 = unpk(v3.y);
    a0 += (p0.x + q0.x) + (r0.x + s0.x);
    a1 += (p0.y + q0.y) + (r0.y + s0.y);
    a2 += (p1.x + q1.x) + (r1.x + s1.x);
    a3 += (p1.y + q1.y) + (r1.y + s1.y);
  }
  for (; i + 8 <= end; i += 8) {
    int n0 = csr[i + g];
    int n1 = csr[i + 4 + g];
    uint2 v0 = *(const uint2*)(table + (size_t)n0 * HD + fq * 4);
    uint2 v1 = *(const uint2*)(table + (size_t)n1 * HD + fq * 4);
    float2 p0 = unpk(v0.x), p1 = unpk(v0.y);
    float2 q0 = unpk(v1.x), q1 = unpk(v1.y);
    a0 += p0.x + q0.x; a1 += p0.y + q0.y;
    a2 += p1.x + q1.x; a3 += p1.y + q1.y;
  }
  for (; i < end; i += 4) {
    int idx = i + g;
    if (idx < end) {
      int nb = csr[idx];
      uint2 v = *(const uint2*)(table + (size_t)nb * HD + fq * 4);
      float2 p0 = unpk(v.x), p1 = unpk(v.y);
      a0 += p0.x; a1 += p0.y; a2 += p1.x; a3 += p1.y;
    }
  }
  a0 += __shfl_xor(a0, 16); a0 += __shfl_xor(a0, 32);
  a1 += __shfl_xor(a1, 16); a1 += __shfl_xor(a1, 32);
  a2 += __shfl_xor(a2, 16); a2 += __shfl_xor(a2, 32);
  a3 += __shfl_xor(a3, 16); a3 += __shfl_xor(a3, 32);
  float inv = 1.0f / fmaxf((float)(end - beg), 1.0f);
  if (lane < 16) {
    float4 o = make_float4(a0 * inv, a1 * inv, a2 * inv, a3 * inv);
    *(float4*)(out + (size_t)row * HD + fq * 4) = o;
  }
}

// ---------------- SAGE linear 64->64 + relu (register-tiled) ----------------

template <int OUTBF>
__global__ __launch_bounds__(256, 3) void sage64_kernel(
    const float* __restrict__ agg, const unsigned short* __restrict__ xd,
    const float* __restrict__ Wl, const float* __restrict__ bl,
    const float* __restrict__ Wr, void* __restrict__ outp, int n) {
  __shared__ float Ws[128][65];     // [k][h], padded (scalar reads only)
  __shared__ float Xs[32][128];     // [row][k] : k<64 agg, k>=64 x
  int t = threadIdx.x;
  int lane = t & 63, wid = t >> 6;
  int row0 = blockIdx.x * 32;
  for (int i = t; i < 4096; i += 256) {
    int h = i >> 6, k = i & 63;
    Ws[k][h] = Wl[i];
  }
  for (int i = t; i < 4096; i += 256) {
    int h = i >> 6, k = i & 63;
    Ws[64 + k][h] = Wr[i];
  }
  for (int i = t; i < 512; i += 256) {
    int r = i >> 4, c4 = i & 15;
    if (row0 + r < n) {
      float4 v = ((const float4*)(agg + (size_t)(row0 + r) * HD))[c4];
      *(float4*)&Xs[r][c4 * 4] = v;
    }
  }
  for (int i = t; i < 512; i += 256) {
    int r = i >> 4, c4 = i & 15;
    if (row0 + r < n) {
      uint2 v = ((const uint2*)(xd + (size_t)(row0 + r) * HD))[c4];
      float2 p0 = unpk(v.x), p1 = unpk(v.y);
      *(float4*)&Xs[r][64 + c4 * 4] = make_float4(p0.x, p0.y, p1.x, p1.y);
    }
  }
  __syncthreads();
  float acc[8] = {0.f, 0.f, 0.f, 0.f, 0.f, 0.f, 0.f, 0.f};
  int rbase = wid * 8;
#pragma unroll 4
  for (int k = 0; k < 128; ++k) {
    float wv = Ws[k][lane];
#pragma unroll
    for (int j = 0; j < 8; ++j) acc[j] += Xs[rbase + j][k] * wv;
  }
  float b = bl[lane];
#pragma unroll
  for (int j = 0; j < 8; ++j) {
    int row = row0 + rbase + j;
    if (row < n) {
      float v = fmaxf(acc[j] + b, 0.f);
      if (OUTBF) ((unsigned short*)outp)[(size_t)row * HD + lane] = f2bf(v);
      else       ((float*)outp)[(size_t)row * HD + lane] = v;
    }
  }
}

// ---------------- layer 2 (z-trick): project u1 -> z[NU][4] ----------------

__global__ __launch_bounds__(256) void zproj_kernel(
    const unsigned short* __restrict__ u1, const float* __restrict__ Wl2,
    float4* __restrict__ z) {
  __shared__ float W[3][64];
  int t = threadIdx.x;
  if (t < 192) W[t / 64][t & 63] = Wl2[t];
  __syncthreads();
  int wid = t >> 6, lane = t & 63;
  int g = lane >> 4, fq = lane & 15;
  int row = blockIdx.x * 16 + wid * 4 + g;
  if (row >= NU) return;
  uint2 v = *(const uint2*)(u1 + (size_t)row * HD + fq * 4);
  float2 p0 = unpk(v.x), p1 = unpk(v.y);
  int f = fq * 4;
  float z0 = p0.x * W[0][f] + p0.y * W[0][f + 1] + p1.x * W[0][f + 2] + p1.y * W[0][f + 3];
  float z1 = p0.x * W[1][f] + p0.y * W[1][f + 1] + p1.x * W[1][f + 2] + p1.y * W[1][f + 3];
  float z2 = p0.x * W[2][f] + p0.y * W[2][f + 1] + p1.x * W[2][f + 2] + p1.y * W[2][f + 3];
#pragma unroll
  for (int off = 1; off < 16; off <<= 1) {
    z0 += __shfl_xor(z0, off);
    z1 += __shfl_xor(z1, off);
    z2 += __shfl_xor(z2, off);
  }
  if (fq == 0) z[row] = make_float4(z0, z1, z2, 0.f);
}

// agg4: mean of z over movie neighborhoods. 16B/edge gather (L2-resident).
__global__ __launch_bounds__(256) void agg4_kernel(
    const float4* __restrict__ z, const int* __restrict__ rp,
    const int* __restrict__ csr, float4* __restrict__ zagg, int n) {
  int wid = threadIdx.x >> 6, lane = threadIdx.x & 63;
  int row = blockIdx.x * 4 + wid;
  if (row >= n) return;
  int beg = rp[row], end = rp[row + 1];
  float s0 = 0.f, s1 = 0.f, s2 = 0.f;
  for (int i = beg + lane; i < end; i += 64) {
    float4 v = z[csr[i]];
    s0 += v.x; s1 += v.y; s2 += v.z;
  }
#pragma unroll
  for (int off = 1; off < 64; off <<= 1) {
    s0 += __shfl_xor(s0, off);
    s1 += __shfl_xor(s1, off);
    s2 += __shfl_xor(s2, off);
  }
  if (lane == 0) {
    float inv = 1.0f / fmaxf((float)(end - beg), 1.0f);
    zagg[row] = make_float4(s0 * inv, s1 * inv, s2 * inv, 0.f);
  }
}

// out2: out[m][g] = zagg[m][g] + bl2[g] + m1[m] . Wr2[g]
__global__ void out2_kernel(const float4* __restrict__ zagg, const float* __restrict__ m1,
                            const float* __restrict__ Wr2, const float* __restrict__ bl2,
                            float* __restrict__ out, int n) {
  int wid = threadIdx.x >> 6, lane = threadIdx.x & 63;
  int row = blockIdx.x * 4 + wid;
  if (row >= n) return;
  float mm = m1[(size_t)row * HD + lane];
  float4 za = zagg[row];
  float zc[3] = {za.x, za.y, za.z};
#pragma unroll
  for (int g = 0; g < 3; ++g) {
    float p = mm * Wr2[g * HD + lane];
#pragma unroll
    for (int off = 32; off > 0; off >>= 1) p += __shfl_down(p, off);
    if (lane == 0) out[row * 3 + g] = p + zc[g] + bl2[g];
  }
}

// ---------------------------------------------------------------------------

extern "C" void kernel_launch(void* const* d_in, const int* in_sizes, int n_in,
                              void* d_out, int out_size, void* d_ws, size_t ws_size,
                              hipStream_t stream) {
  const float* x_user  = (const float*)d_in[0];
  const float* x_movie = (const float*)d_in[1];
  const int*   e_src   = (const int*)d_in[2];
  const int*   e_dst   = (const int*)d_in[3];
  const float* W_user  = (const float*)d_in[4];
  const float* b_user  = (const float*)d_in[5];
  const float* W_movie = (const float*)d_in[6];
  const float* b_movie = (const float*)d_in[7];
  const float* Wl1_um  = (const float*)d_in[8];
  const float* bl1_um  = (const float*)d_in[9];
  const float* Wr1_um  = (const float*)d_in[10];
  const float* Wl1_mu  = (const float*)d_in[11];
  const float* bl1_mu  = (const float*)d_in[12];
  const float* Wr1_mu  = (const float*)d_in[13];
  const float* Wl2_um  = (const float*)d_in[14];
  const float* bl2_um  = (const float*)d_in[15];
  const float* Wr2_um  = (const float*)d_in[16];
  float* outp = (float*)d_out;

  // ---- workspace carve-up ----
  char* p = (char*)d_ws;
  size_t off = 0;
  auto take = [&](size_t bytes) { void* r = p + off; off += alignup(bytes); return r; };

  int* rp_m    = (int*)take(size_t(NM + 1) * 4);
  int* rp_u    = (int*)take(size_t(NU + 1) * 4);
  int* bh      = (int*)take(size_t(NBK) * 4);
  int* bbase_m = (int*)take(size_t(MBK + 1) * 4);
  int* bbase_u = (int*)take(size_t(UBK + 1) * 4);
  int* bcur_m  = (int*)take(size_t(MBK) * 4);
  int* bcur_u  = (int*)take(size_t(UBK) * 4);
  int* csr_m   = (int*)take(size_t(NE) * 4);
  int* csr_u   = (int*)take(size_t(NE) * 4);

  // overlay: staging (build phase) aliases feature buffers (feature phase)
  size_t ov_base = off;
  unsigned* stage_m = (unsigned*)take(size_t(NE) * 4);
  unsigned* stage_u = (unsigned*)take(size_t(NE) * 4);
  size_t stage_end = off;
  off = ov_base;
  unsigned short* hu = (unsigned short*)take(size_t(NU) * HD * 2);
  unsigned short* hm = (unsigned short*)take(size_t(NM) * HD * 2);
  unsigned short* u1 = (unsigned short*)take(size_t(NU) * HD * 2);
  float* m1   = (float*)take(size_t(NM) * HD * 4);
  float* aggb = (float*)take(size_t(NU) * HD * 4);
  if (off < stage_end) off = stage_end;
  float4* z    = (float4*)take(size_t(NU) * 16);
  float4* zagg = (float4*)take(size_t(NM) * 16);
  unsigned short* Wb = (unsigned short*)take(size_t(HD) * FM * 2);
  if (off > ws_size) return;

  const int TB = 256;

  // ---- CSR build ----
  hipMemsetAsync(bh, 0, size_t(NBK) * 4, stream);
  histB_kernel<<<512, 256, 0, stream>>>(e_src, e_dst, bh);
  scanB_kernel<<<1, 1024, 0, stream>>>(bh, bbase_m, bbase_u, bcur_m, bcur_u);
  passA_kernel<<<(NE + EPB - 1) / EPB, 1024, 0, stream>>>(e_src, e_dst, bcur_m, bcur_u,
                                                          stage_m, stage_u);
  passB_kernel<<<NBK, 1024, 0, stream>>>(bbase_m, bbase_u, stage_m, stage_u,
                                         csr_m, csr_u, rp_m, rp_u);

  // ---- projections ----
  convW_kernel<<<(HD * FM + 255) / 256, 256, 0, stream>>>(W_movie, Wb, HD * FM);
  proj_user_kernel<<<NU / 16, TB, 0, stream>>>(x_user, W_user, b_user, hu);
  proj_movie_kernel<<<(NM + 63) / 64, TB, 0, stream>>>(x_movie, Wb, b_movie, hm);

  // ---- layer 1: movie side ----
  agg_mean_kernel<<<(NM + 3) / 4, TB, 0, stream>>>(hu, rp_m, csr_m, aggb, NM);
  sage64_kernel<0><<<(NM + 31) / 32, TB, 0, stream>>>(aggb, hm, Wl1_um, bl1_um, Wr1_um, m1, NM);

  // ---- layer 1: user side ----
  agg_mean_kernel<<<(NU + 3) / 4, TB, 0, stream>>>(hm, rp_u, csr_u, aggb, NU);
  sage64_kernel<1><<<(NU + 31) / 32, TB, 0, stream>>>(aggb, hu, Wl1_mu, bl1_mu, Wr1_mu, u1, NU);

  // ---- layer 2 (z-trick): project u1 -> z, aggregate z, combine ----
  zproj_kernel<<<(NU + 15) / 16, TB, 0, stream>>>(u1, Wl2_um, z);
  agg4_kernel<<<(NM + 3) / 4, TB, 0, stream>>>(z, rp_m, csr_m, zagg, NM);
  out2_kernel<<<(NM + 3) / 4, TB, 0, stream>>>(zagg, m1, Wr2_um, bl2_um, outp, NM);
}

// Round 12
// 392.438 us; speedup vs baseline: 1.1637x; 1.1637x over previous
//
#include <hip/hip_runtime.h>

// ---------------------------------------------------------------------------
// Hetero GraphSAGE (user<->movie). Bucketed CSR build, bf16 gather tables,
// MFMA movie projection + MFMA SAGE linear, layer-2 z-trick.
// ---------------------------------------------------------------------------

constexpr int NU = 100000;   // users
constexpr int NM = 50000;    // movies
constexpr int NE = 4000000;  // edges
constexpr int FU = 24;       // user feat
constexpr int FM = 404;      // movie feat
constexpr int HD = 64;       // hidden

constexpr int BSH = 8;                       // bucket = 256 node ids
constexpr int MBK = (NM + 255) >> BSH;       // 196 movie buckets
constexpr int UBK = (NU + 255) >> BSH;       // 391 user buckets
constexpr int NBK = MBK + UBK;               // 587
constexpr int EPB = 8192;                    // edges per passA block (1024 thr x 8)

static inline size_t alignup(size_t x) { return (x + 255) & ~size_t(255); }

__device__ __forceinline__ float bf2f(unsigned short h) {
  return __uint_as_float(((unsigned int)h) << 16);
}
__device__ __forceinline__ unsigned short f2bf(float f) {
  unsigned int u = __float_as_uint(f);
  u = (u + 0x7FFFu + ((u >> 16) & 1u)) >> 16;   // RNE
  return (unsigned short)u;
}
__device__ __forceinline__ float2 unpk(unsigned u) {
  return make_float2(__uint_as_float(u << 16), __uint_as_float(u & 0xFFFF0000u));
}

using bf16x8 = __attribute__((ext_vector_type(8))) short;   // 8 bf16 = 4 VGPRs
using f32x4  = __attribute__((ext_vector_type(4))) float;   // MFMA C/D frag

// ---------------- CSR build ----------------

__global__ __launch_bounds__(256) void histB_kernel(const int* __restrict__ src,
                                                    const int* __restrict__ dst,
                                                    int* __restrict__ bh) {
  __shared__ int h[NBK];
  for (int i = threadIdx.x; i < NBK; i += 256) h[i] = 0;
  __syncthreads();
  int idx = blockIdx.x * 256 + threadIdx.x;
  int stride = gridDim.x * 256;
  for (int i = idx; i < NE; i += stride) {
    atomicAdd(&h[dst[i] >> BSH], 1);
    atomicAdd(&h[MBK + (src[i] >> BSH)], 1);
  }
  __syncthreads();
  for (int i = threadIdx.x; i < NBK; i += 256) {
    int c = h[i];
    if (c) atomicAdd(&bh[i], c);
  }
}

__global__ __launch_bounds__(1024) void scanB_kernel(const int* __restrict__ bh,
                                                     int* __restrict__ bbase_m,
                                                     int* __restrict__ bbase_u,
                                                     int* __restrict__ bcur_m,
                                                     int* __restrict__ bcur_u) {
  __shared__ int tmp[1024];
  int t = threadIdx.x;
  int vm = (t < MBK) ? bh[t] : 0;
  tmp[t] = vm;
  __syncthreads();
  for (int off = 1; off < 1024; off <<= 1) {
    int v = (t >= off) ? tmp[t - off] : 0;
    __syncthreads();
    tmp[t] += v;
    __syncthreads();
  }
  if (t < MBK) {
    int e = tmp[t] - vm;
    bbase_m[t] = e; bcur_m[t] = e;
    if (t == MBK - 1) bbase_m[MBK] = tmp[t];
  }
  __syncthreads();
  int vu = (t < UBK) ? bh[MBK + t] : 0;
  tmp[t] = vu;
  __syncthreads();
  for (int off = 1; off < 1024; off <<= 1) {
    int v = (t >= off) ? tmp[t - off] : 0;
    __syncthreads();
    tmp[t] += v;
    __syncthreads();
  }
  if (t < UBK) {
    int e = tmp[t] - vu;
    bbase_u[t] = e; bcur_u[t] = e;
    if (t == UBK - 1) bbase_u[UBK] = tmp[t];
  }
}

// Pass A (round-10 config: EPB=8192, 8 items/thread, 48% occupancy)
__global__ __launch_bounds__(1024) void passA_kernel(
    const int* __restrict__ src, const int* __restrict__ dst,
    int* __restrict__ bcur_m, int* __restrict__ bcur_u,
    unsigned* __restrict__ stage_m, unsigned* __restrict__ stage_u) {
  __shared__ int hB[NBK];
  int t = threadIdx.x;
  for (int i = t; i < NBK; i += 1024) hB[i] = 0;
  __syncthreads();
  int e0 = blockIdx.x * EPB + t;
  int sv[8], dv[8], rm[8], ru[8];
#pragma unroll
  for (int k = 0; k < 8; ++k) {
    int e = e0 + k * 1024;
    if (e < NE) {
      int s = src[e], d = dst[e];
      sv[k] = s; dv[k] = d;
      rm[k] = atomicAdd(&hB[d >> BSH], 1);
      ru[k] = atomicAdd(&hB[MBK + (s >> BSH)], 1);
    } else {
      sv[k] = -1;
    }
  }
  __syncthreads();
  for (int i = t; i < NBK; i += 1024) {
    int c = hB[i];
    int base = 0;
    if (c) base = (i < MBK) ? atomicAdd(&bcur_m[i], c) : atomicAdd(&bcur_u[i - MBK], c);
    hB[i] = base;
  }
  __syncthreads();
#pragma unroll
  for (int k = 0; k < 8; ++k) {
    if (sv[k] >= 0) {
      int s = sv[k], d = dv[k];
      stage_m[hB[d >> BSH] + rm[k]] = ((unsigned)(d & 255) << 24) | (unsigned)s;
      stage_u[hB[MBK + (s >> BSH)] + ru[k]] = ((unsigned)(s & 255) << 24) | (unsigned)d;
    }
  }
}

__global__ __launch_bounds__(1024) void passB_kernel(
    const int* __restrict__ bbase_m, const int* __restrict__ bbase_u,
    const unsigned* __restrict__ stage_m, const unsigned* __restrict__ stage_u,
    int* __restrict__ csr_m, int* __restrict__ csr_u,
    int* __restrict__ rp_m, int* __restrict__ rp_u) {
  __shared__ int cnt[256];
  __shared__ int sc[256];
  int b = blockIdx.x;
  const unsigned* stage; int* csr; int* rp; int idbase, ntot, bb, be;
  if (b < MBK) {
    stage = stage_m; csr = csr_m; rp = rp_m;
    idbase = b << BSH; ntot = NM;
    bb = bbase_m[b]; be = bbase_m[b + 1];
  } else {
    int c = b - MBK;
    stage = stage_u; csr = csr_u; rp = rp_u;
    idbase = c << BSH; ntot = NU;
    bb = bbase_u[c]; be = bbase_u[c + 1];
  }
  int nloc = min(256, ntot - idbase);
  int t = threadIdx.x;
  if (t < 256) cnt[t] = 0;
  __syncthreads();
  for (int j = bb + t; j < be; j += 1024) atomicAdd(&cnt[stage[j] >> 24], 1);
  __syncthreads();
  int c0 = (t < 256) ? cnt[t] : 0;
  if (t < 256) sc[t] = c0;
  __syncthreads();
  for (int off = 1; off < 256; off <<= 1) {
    int v = 0;
    if (t < 256 && t >= off) v = sc[t - off];
    __syncthreads();
    if (t < 256) sc[t] += v;
    __syncthreads();
  }
  if (t < nloc) {
    int e = bb + sc[t] - c0;
    rp[idbase + t] = e;
    cnt[t] = e;                     // reuse as cursor
  }
  if (t == 0 && idbase + nloc == ntot) rp[ntot] = be;
  __syncthreads();
  for (int j = bb + t; j < be; j += 1024) {
    unsigned e = stage[j];
    int pos = atomicAdd(&cnt[e >> 24], 1);
    csr[pos] = (int)(e & 0xFFFFFFu);
  }
}

// ---------------- input projections (write bf16 tables) ----------------

__global__ void proj_user_kernel(const float* __restrict__ xu, const float* __restrict__ Wu,
                                 const float* __restrict__ bu, unsigned short* __restrict__ hu) {
  __shared__ float Wt[FU][HD + 1];
  __shared__ float Xl[16][FU];
  int t = threadIdx.x;
  int lane = t & 63, wg = t >> 6;
  int row0 = blockIdx.x * 16;
  for (int h = wg; h < HD; h += 4)
    if (lane < FU) Wt[lane][h] = Wu[h * FU + lane];
  for (int r = wg; r < 16; r += 4)
    if (lane < FU) Xl[r][lane] = xu[(row0 + r) * FU + lane];
  __syncthreads();
  float b = bu[lane];
  float acc[4] = {0.f, 0.f, 0.f, 0.f};
  for (int k = 0; k < FU; ++k) {
    float w = Wt[k][lane];
#pragma unroll
    for (int j = 0; j < 4; ++j) acc[j] += Xl[wg * 4 + j][k] * w;
  }
#pragma unroll
  for (int j = 0; j < 4; ++j)
    hu[(row0 + wg * 4 + j) * HD + lane] = f2bf(acc[j] + b);
}

// W_movie fp32 -> bf16 (once per launch)
__global__ void convW_kernel(const float* __restrict__ W, unsigned short* __restrict__ Wb,
                             int n) {
  int i = blockIdx.x * 256 + threadIdx.x;
  if (i < n) Wb[i] = f2bf(W[i]);
}

// [Wl | Wr] -> bf16 Wb2[h][128]  (k<64 from Wl, k>=64 from Wr)
__global__ void convW2_kernel(const float* __restrict__ Wl, const float* __restrict__ Wr,
                              unsigned short* __restrict__ Wb2) {
  int i = blockIdx.x * 256 + threadIdx.x;
  if (i < HD * 128) {
    int h = i >> 7, k = i & 127;
    float v = (k < 64) ? Wl[h * 64 + k] : Wr[h * 64 + (k - 64)];
    Wb2[i] = f2bf(v);
  }
}

// Movie projection via MFMA (round-10 config, verified).
__global__ __launch_bounds__(256) void proj_movie_kernel(
    const float* __restrict__ xm, const unsigned short* __restrict__ Wb,
    const float* __restrict__ bm, unsigned short* __restrict__ hm) {
  __shared__ unsigned short Xs[64][72];
  __shared__ unsigned short Ws[64][72];
  int t = threadIdx.x;
  int lane = t & 63, wid = t >> 6;
  int row0 = blockIdx.x * 64;
  int r0 = wid * 16;
  f32x4 acc[4];
#pragma unroll
  for (int nt = 0; nt < 4; ++nt) acc[nt] = (f32x4){0.f, 0.f, 0.f, 0.f};

  for (int k0 = 0; k0 < 448; k0 += 64) {
    int kc = min(64, FM - k0);
    __syncthreads();
    for (int i = t; i < 1024; i += 256) {
      int r = i >> 4, c4 = i & 15;
      float4 v = make_float4(0.f, 0.f, 0.f, 0.f);
      if (c4 * 4 < kc && row0 + r < NM)
        v = *(const float4*)(xm + (size_t)(row0 + r) * FM + k0 + c4 * 4);
      ushort4 o;
      o.x = f2bf(v.x); o.y = f2bf(v.y); o.z = f2bf(v.z); o.w = f2bf(v.w);
      *(ushort4*)&Xs[r][c4 * 4] = o;
    }
    for (int i = t; i < 1024; i += 256) {
      int h = i >> 4, c4 = i & 15;
      uint2 v = make_uint2(0u, 0u);
      if (c4 * 4 < kc)
        v = *(const uint2*)(Wb + (size_t)h * FM + k0 + c4 * 4);
      *(uint2*)&Ws[h][c4 * 4] = v;
    }
    __syncthreads();
#pragma unroll
    for (int kk = 0; kk < 64; kk += 32) {
      bf16x8 a = *(const bf16x8*)&Xs[r0 + (lane & 15)][kk + (lane >> 4) * 8];
#pragma unroll
      for (int nt = 0; nt < 4; ++nt) {
        bf16x8 b = *(const bf16x8*)&Ws[nt * 16 + (lane & 15)][kk + (lane >> 4) * 8];
        acc[nt] = __builtin_amdgcn_mfma_f32_16x16x32_bf16(a, b, acc[nt], 0, 0, 0);
      }
    }
  }
  int col = lane & 15;
  int rbase = r0 + (lane >> 4) * 4;
#pragma unroll
  for (int nt = 0; nt < 4; ++nt) {
    float b = bm[nt * 16 + col];
#pragma unroll
    for (int j = 0; j < 4; ++j) {
      int row = row0 + rbase + j;
      if (row < NM)
        hm[(size_t)row * HD + nt * 16 + col] = f2bf(acc[nt][j] + b);
    }
  }
}

// ---------------- mean aggregation (bf16 out): 4 nbrs/wave, 16-deep -------

__global__ __launch_bounds__(256) void agg_mean_kernel(
    const unsigned short* __restrict__ table, const int* __restrict__ rp,
    const int* __restrict__ csr, unsigned short* __restrict__ out, int n) {
  int wid = threadIdx.x >> 6;
  int lane = threadIdx.x & 63;
  int row = blockIdx.x * 4 + wid;
  if (row >= n) return;
  int beg = rp[row], end = rp[row + 1];
  int g = lane >> 4;        // neighbor slot 0..3
  int fq = lane & 15;       // feature quad
  float a0 = 0.f, a1 = 0.f, a2 = 0.f, a3 = 0.f;
  int i = beg;
  for (; i + 16 <= end; i += 16) {
    int n0 = csr[i + g];
    int n1 = csr[i + 4 + g];
    int n2 = csr[i + 8 + g];
    int n3 = csr[i + 12 + g];
    uint2 v0 = *(const uint2*)(table + (size_t)n0 * HD + fq * 4);
    uint2 v1 = *(const uint2*)(table + (size_t)n1 * HD + fq * 4);
    uint2 v2 = *(const uint2*)(table + (size_t)n2 * HD + fq * 4);
    uint2 v3 = *(const uint2*)(table + (size_t)n3 * HD + fq * 4);
    float2 p0 = unpk(v0.x), p1 = unpk(v0.y);
    float2 q0 = unpk(v1.x), q1 = unpk(v1.y);
    float2 r0 = unpk(v2.x), r1 = unpk(v2.y);
    float2 s0 = unpk(v3.x), s1 = unpk(v3.y);
    a0 += (p0.x + q0.x) + (r0.x + s0.x);
    a1 += (p0.y + q0.y) + (r0.y + s0.y);
    a2 += (p1.x + q1.x) + (r1.x + s1.x);
    a3 += (p1.y + q1.y) + (r1.y + s1.y);
  }
  for (; i + 8 <= end; i += 8) {
    int n0 = csr[i + g];
    int n1 = csr[i + 4 + g];
    uint2 v0 = *(const uint2*)(table + (size_t)n0 * HD + fq * 4);
    uint2 v1 = *(const uint2*)(table + (size_t)n1 * HD + fq * 4);
    float2 p0 = unpk(v0.x), p1 = unpk(v0.y);
    float2 q0 = unpk(v1.x), q1 = unpk(v1.y);
    a0 += p0.x + q0.x; a1 += p0.y + q0.y;
    a2 += p1.x + q1.x; a3 += p1.y + q1.y;
  }
  for (; i < end; i += 4) {
    int idx = i + g;
    if (idx < end) {
      int nb = csr[idx];
      uint2 v = *(const uint2*)(table + (size_t)nb * HD + fq * 4);
      float2 p0 = unpk(v.x), p1 = unpk(v.y);
      a0 += p0.x; a1 += p0.y; a2 += p1.x; a3 += p1.y;
    }
  }
  a0 += __shfl_xor(a0, 16); a0 += __shfl_xor(a0, 32);
  a1 += __shfl_xor(a1, 16); a1 += __shfl_xor(a1, 32);
  a2 += __shfl_xor(a2, 16); a2 += __shfl_xor(a2, 32);
  a3 += __shfl_xor(a3, 16); a3 += __shfl_xor(a3, 32);
  float inv = 1.0f / fmaxf((float)(end - beg), 1.0f);
  if (lane < 16) {
    ushort4 o;
    o.x = f2bf(a0 * inv); o.y = f2bf(a1 * inv);
    o.z = f2bf(a2 * inv); o.w = f2bf(a3 * inv);
    *(ushort4*)(out + (size_t)row * HD + fq * 4) = o;
  }
}

// ---------------- SAGE linear via MFMA: [n x 128] @ Wb2^T + bl, relu ------
// Same structure/layout as proj_movie (verified): 64-row block, 4 waves,
// each wave 16 rows x 64 cols, K=128 in 4 chunks of 32.

template <int OUTBF>
__global__ __launch_bounds__(256) void sage64_kernel(
    const unsigned short* __restrict__ agg, const unsigned short* __restrict__ xd,
    const unsigned short* __restrict__ Wb2, const float* __restrict__ bl,
    void* __restrict__ outp, int n) {
  __shared__ unsigned short Xs[64][136];   // [r][k], k<64 agg | k>=64 x
  __shared__ unsigned short Ws[64][136];   // [h][k]
  int t = threadIdx.x;
  int lane = t & 63, wid = t >> 6;
  int row0 = blockIdx.x * 64;
  int r0 = wid * 16;
  // stage W: 64 rows x 16 uint4 groups (8 bf16 each)
  for (int i = t; i < 1024; i += 256) {
    int h = i >> 4, g = i & 15;
    *(uint4*)&Ws[h][g * 8] = *(const uint4*)(Wb2 + (size_t)h * 128 + g * 8);
  }
  // stage X: 64 rows x 16 uint4 groups; g<8 from agg, g>=8 from xd
  for (int i = t; i < 1024; i += 256) {
    int r = i >> 4, g = i & 15;
    uint4 v = make_uint4(0u, 0u, 0u, 0u);
    if (row0 + r < n) {
      if (g < 8) v = *(const uint4*)(agg + (size_t)(row0 + r) * HD + g * 8);
      else       v = *(const uint4*)(xd + (size_t)(row0 + r) * HD + (g - 8) * 8);
    }
    *(uint4*)&Xs[r][g * 8] = v;
  }
  __syncthreads();
  f32x4 acc[4];
#pragma unroll
  for (int nt = 0; nt < 4; ++nt) acc[nt] = (f32x4){0.f, 0.f, 0.f, 0.f};
#pragma unroll
  for (int kk = 0; kk < 128; kk += 32) {
    bf16x8 a = *(const bf16x8*)&Xs[r0 + (lane & 15)][kk + (lane >> 4) * 8];
#pragma unroll
    for (int nt = 0; nt < 4; ++nt) {
      bf16x8 b = *(const bf16x8*)&Ws[nt * 16 + (lane & 15)][kk + (lane >> 4) * 8];
      acc[nt] = __builtin_amdgcn_mfma_f32_16x16x32_bf16(a, b, acc[nt], 0, 0, 0);
    }
  }
  int col = lane & 15;
  int rbase = r0 + (lane >> 4) * 4;
#pragma unroll
  for (int nt = 0; nt < 4; ++nt) {
    float b = bl[nt * 16 + col];
#pragma unroll
    for (int j = 0; j < 4; ++j) {
      int row = row0 + rbase + j;
      if (row < n) {
        float v = fmaxf(acc[nt][j] + b, 0.f);
        if (OUTBF) ((unsigned short*)outp)[(size_t)row * HD + nt * 16 + col] = f2bf(v);
        else       ((float*)outp)[(size_t)row * HD + nt * 16 + col] = v;
      }
    }
  }
}

// ---------------- layer 2 (z-trick): project u1 -> z[NU][4] ----------------

__global__ __launch_bounds__(256) void zproj_kernel(
    const unsigned short* __restrict__ u1, const float* __restrict__ Wl2,
    float4* __restrict__ z) {
  __shared__ float W[3][64];
  int t = threadIdx.x;
  if (t < 192) W[t / 64][t & 63] = Wl2[t];
  __syncthreads();
  int wid = t >> 6, lane = t & 63;
  int g = lane >> 4, fq = lane & 15;
  int row = blockIdx.x * 16 + wid * 4 + g;
  if (row >= NU) return;
  uint2 v = *(const uint2*)(u1 + (size_t)row * HD + fq * 4);
  float2 p0 = unpk(v.x), p1 = unpk(v.y);
  int f = fq * 4;
  float z0 = p0.x * W[0][f] + p0.y * W[0][f + 1] + p1.x * W[0][f + 2] + p1.y * W[0][f + 3];
  float z1 = p0.x * W[1][f] + p0.y * W[1][f + 1] + p1.x * W[1][f + 2] + p1.y * W[1][f + 3];
  float z2 = p0.x * W[2][f] + p0.y * W[2][f + 1] + p1.x * W[2][f + 2] + p1.y * W[2][f + 3];
#pragma unroll
  for (int off = 1; off < 16; off <<= 1) {
    z0 += __shfl_xor(z0, off);
    z1 += __shfl_xor(z1, off);
    z2 += __shfl_xor(z2, off);
  }
  if (fq == 0) z[row] = make_float4(z0, z1, z2, 0.f);
}

// agg4: mean of z over movie neighborhoods. 16B/edge gather (L2-resident).
__global__ __launch_bounds__(256) void agg4_kernel(
    const float4* __restrict__ z, const int* __restrict__ rp,
    const int* __restrict__ csr, float4* __restrict__ zagg, int n) {
  int wid = threadIdx.x >> 6, lane = threadIdx.x & 63;
  int row = blockIdx.x * 4 + wid;
  if (row >= n) return;
  int beg = rp[row], end = rp[row + 1];
  float s0 = 0.f, s1 = 0.f, s2 = 0.f;
  for (int i = beg + lane; i < end; i += 64) {
    float4 v = z[csr[i]];
    s0 += v.x; s1 += v.y; s2 += v.z;
  }
#pragma unroll
  for (int off = 1; off < 64; off <<= 1) {
    s0 += __shfl_xor(s0, off);
    s1 += __shfl_xor(s1, off);
    s2 += __shfl_xor(s2, off);
  }
  if (lane == 0) {
    float inv = 1.0f / fmaxf((float)(end - beg), 1.0f);
    zagg[row] = make_float4(s0 * inv, s1 * inv, s2 * inv, 0.f);
  }
}

// out2: out[m][g] = zagg[m][g] + bl2[g] + m1[m] . Wr2[g]
__global__ void out2_kernel(const float4* __restrict__ zagg, const float* __restrict__ m1,
                            const float* __restrict__ Wr2, const float* __restrict__ bl2,
                            float* __restrict__ out, int n) {
  int wid = threadIdx.x >> 6, lane = threadIdx.x & 63;
  int row = blockIdx.x * 4 + wid;
  if (row >= n) return;
  float mm = m1[(size_t)row * HD + lane];
  float4 za = zagg[row];
  float zc[3] = {za.x, za.y, za.z};
#pragma unroll
  for (int g = 0; g < 3; ++g) {
    float p = mm * Wr2[g * HD + lane];
#pragma unroll
    for (int off = 32; off > 0; off >>= 1) p += __shfl_down(p, off);
    if (lane == 0) out[row * 3 + g] = p + zc[g] + bl2[g];
  }
}

// ---------------------------------------------------------------------------

extern "C" void kernel_launch(void* const* d_in, const int* in_sizes, int n_in,
                              void* d_out, int out_size, void* d_ws, size_t ws_size,
                              hipStream_t stream) {
  const float* x_user  = (const float*)d_in[0];
  const float* x_movie = (const float*)d_in[1];
  const int*   e_src   = (const int*)d_in[2];
  const int*   e_dst   = (const int*)d_in[3];
  const float* W_user  = (const float*)d_in[4];
  const float* b_user  = (const float*)d_in[5];
  const float* W_movie = (const float*)d_in[6];
  const float* b_movie = (const float*)d_in[7];
  const float* Wl1_um  = (const float*)d_in[8];
  const float* bl1_um  = (const float*)d_in[9];
  const float* Wr1_um  = (const float*)d_in[10];
  const float* Wl1_mu  = (const float*)d_in[11];
  const float* bl1_mu  = (const float*)d_in[12];
  const float* Wr1_mu  = (const float*)d_in[13];
  const float* Wl2_um  = (const float*)d_in[14];
  const float* bl2_um  = (const float*)d_in[15];
  const float* Wr2_um  = (const float*)d_in[16];
  float* outp = (float*)d_out;

  // ---- workspace carve-up ----
  char* p = (char*)d_ws;
  size_t off = 0;
  auto take = [&](size_t bytes) { void* r = p + off; off += alignup(bytes); return r; };

  int* rp_m    = (int*)take(size_t(NM + 1) * 4);
  int* rp_u    = (int*)take(size_t(NU + 1) * 4);
  int* bh      = (int*)take(size_t(NBK) * 4);
  int* bbase_m = (int*)take(size_t(MBK + 1) * 4);
  int* bbase_u = (int*)take(size_t(UBK + 1) * 4);
  int* bcur_m  = (int*)take(size_t(MBK) * 4);
  int* bcur_u  = (int*)take(size_t(UBK) * 4);
  int* csr_m   = (int*)take(size_t(NE) * 4);
  int* csr_u   = (int*)take(size_t(NE) * 4);

  // overlay: staging (build phase) aliases feature buffers (feature phase)
  size_t ov_base = off;
  unsigned* stage_m = (unsigned*)take(size_t(NE) * 4);
  unsigned* stage_u = (unsigned*)take(size_t(NE) * 4);
  size_t stage_end = off;
  off = ov_base;
  unsigned short* hu = (unsigned short*)take(size_t(NU) * HD * 2);
  unsigned short* hm = (unsigned short*)take(size_t(NM) * HD * 2);
  unsigned short* u1 = (unsigned short*)take(size_t(NU) * HD * 2);
  float* m1   = (float*)take(size_t(NM) * HD * 4);
  unsigned short* aggb = (unsigned short*)take(size_t(NU) * HD * 2);
  if (off < stage_end) off = stage_end;
  float4* z    = (float4*)take(size_t(NU) * 16);
  float4* zagg = (float4*)take(size_t(NM) * 16);
  unsigned short* Wb   = (unsigned short*)take(size_t(HD) * FM * 2);
  unsigned short* Wum  = (unsigned short*)take(size_t(HD) * 128 * 2);
  unsigned short* Wmu  = (unsigned short*)take(size_t(HD) * 128 * 2);
  if (off > ws_size) return;

  const int TB = 256;

  // ---- CSR build ----
  hipMemsetAsync(bh, 0, size_t(NBK) * 4, stream);
  histB_kernel<<<512, 256, 0, stream>>>(e_src, e_dst, bh);
  scanB_kernel<<<1, 1024, 0, stream>>>(bh, bbase_m, bbase_u, bcur_m, bcur_u);
  passA_kernel<<<(NE + EPB - 1) / EPB, 1024, 0, stream>>>(e_src, e_dst, bcur_m, bcur_u,
                                                          stage_m, stage_u);
  passB_kernel<<<NBK, 1024, 0, stream>>>(bbase_m, bbase_u, stage_m, stage_u,
                                         csr_m, csr_u, rp_m, rp_u);

  // ---- projections + weight conversions ----
  convW_kernel<<<(HD * FM + 255) / 256, 256, 0, stream>>>(W_movie, Wb, HD * FM);
  convW2_kernel<<<(HD * 128 + 255) / 256, 256, 0, stream>>>(Wl1_um, Wr1_um, Wum);
  convW2_kernel<<<(HD * 128 + 255) / 256, 256, 0, stream>>>(Wl1_mu, Wr1_mu, Wmu);
  proj_user_kernel<<<NU / 16, TB, 0, stream>>>(x_user, W_user, b_user, hu);
  proj_movie_kernel<<<(NM + 63) / 64, TB, 0, stream>>>(x_movie, Wb, b_movie, hm);

  // ---- layer 1: movie side ----
  agg_mean_kernel<<<(NM + 3) / 4, TB, 0, stream>>>(hu, rp_m, csr_m, aggb, NM);
  sage64_kernel<0><<<(NM + 63) / 64, TB, 0, stream>>>(aggb, hm, Wum, bl1_um, m1, NM);

  // ---- layer 1: user side ----
  agg_mean_kernel<<<(NU + 3) / 4, TB, 0, stream>>>(hm, rp_u, csr_u, aggb, NU);
  sage64_kernel<1><<<(NU + 63) / 64, TB, 0, stream>>>(aggb, hu, Wmu, bl1_mu, u1, NU);

  // ---- layer 2 (z-trick): project u1 -> z, aggregate z, combine ----
  zproj_kernel<<<(NU + 15) / 16, TB, 0, stream>>>(u1, Wl2_um, z);
  agg4_kernel<<<(NM + 3) / 4, TB, 0, stream>>>(z, rp_m, csr_m, zagg, NM);
  out2_kernel<<<(NM + 3) / 4, TB, 0, stream>>>(zagg, m1, Wr2_um, bl2_um, outp, NM);
}

// Round 13
// 382.787 us; speedup vs baseline: 1.1930x; 1.0252x over previous
//
#include <hip/hip_runtime.h>

// ---------------------------------------------------------------------------
// Hetero GraphSAGE (user<->movie). Bucketed CSR build, bf16 gather tables,
// MFMA GEMMs, movie-side aggregation in 24-dim input space (agg/proj commute),
// layer-2 z-trick.
// ---------------------------------------------------------------------------

constexpr int NU = 100000;   // users
constexpr int NM = 50000;    // movies
constexpr int NE = 4000000;  // edges
constexpr int FU = 24;       // user feat
constexpr int FM = 404;      // movie feat
constexpr int HD = 64;       // hidden

constexpr int BSH = 8;                       // bucket = 256 node ids
constexpr int MBK = (NM + 255) >> BSH;       // 196 movie buckets
constexpr int UBK = (NU + 255) >> BSH;       // 391 user buckets
constexpr int NBK = MBK + UBK;               // 587
constexpr int EPB = 8192;                    // edges per passA block (1024 thr x 8)

static inline size_t alignup(size_t x) { return (x + 255) & ~size_t(255); }

__device__ __forceinline__ float bf2f(unsigned short h) {
  return __uint_as_float(((unsigned int)h) << 16);
}
__device__ __forceinline__ unsigned short f2bf(float f) {
  unsigned int u = __float_as_uint(f);
  u = (u + 0x7FFFu + ((u >> 16) & 1u)) >> 16;   // RNE
  return (unsigned short)u;
}
__device__ __forceinline__ float2 unpk(unsigned u) {
  return make_float2(__uint_as_float(u << 16), __uint_as_float(u & 0xFFFF0000u));
}

using bf16x8 = __attribute__((ext_vector_type(8))) short;   // 8 bf16 = 4 VGPRs
using f32x4  = __attribute__((ext_vector_type(4))) float;   // MFMA C/D frag

// ---------------- CSR build ----------------

__global__ __launch_bounds__(256) void histB_kernel(const int* __restrict__ src,
                                                    const int* __restrict__ dst,
                                                    int* __restrict__ bh) {
  __shared__ int h[NBK];
  for (int i = threadIdx.x; i < NBK; i += 256) h[i] = 0;
  __syncthreads();
  int idx = blockIdx.x * 256 + threadIdx.x;
  int stride = gridDim.x * 256;
  for (int i = idx; i < NE; i += stride) {
    atomicAdd(&h[dst[i] >> BSH], 1);
    atomicAdd(&h[MBK + (src[i] >> BSH)], 1);
  }
  __syncthreads();
  for (int i = threadIdx.x; i < NBK; i += 256) {
    int c = h[i];
    if (c) atomicAdd(&bh[i], c);
  }
}

__global__ __launch_bounds__(1024) void scanB_kernel(const int* __restrict__ bh,
                                                     int* __restrict__ bbase_m,
                                                     int* __restrict__ bbase_u,
                                                     int* __restrict__ bcur_m,
                                                     int* __restrict__ bcur_u) {
  __shared__ int tmp[1024];
  int t = threadIdx.x;
  int vm = (t < MBK) ? bh[t] : 0;
  tmp[t] = vm;
  __syncthreads();
  for (int off = 1; off < 1024; off <<= 1) {
    int v = (t >= off) ? tmp[t - off] : 0;
    __syncthreads();
    tmp[t] += v;
    __syncthreads();
  }
  if (t < MBK) {
    int e = tmp[t] - vm;
    bbase_m[t] = e; bcur_m[t] = e;
    if (t == MBK - 1) bbase_m[MBK] = tmp[t];
  }
  __syncthreads();
  int vu = (t < UBK) ? bh[MBK + t] : 0;
  tmp[t] = vu;
  __syncthreads();
  for (int off = 1; off < 1024; off <<= 1) {
    int v = (t >= off) ? tmp[t - off] : 0;
    __syncthreads();
    tmp[t] += v;
    __syncthreads();
  }
  if (t < UBK) {
    int e = tmp[t] - vu;
    bbase_u[t] = e; bcur_u[t] = e;
    if (t == UBK - 1) bbase_u[UBK] = tmp[t];
  }
}

__global__ __launch_bounds__(1024) void passA_kernel(
    const int* __restrict__ src, const int* __restrict__ dst,
    int* __restrict__ bcur_m, int* __restrict__ bcur_u,
    unsigned* __restrict__ stage_m, unsigned* __restrict__ stage_u) {
  __shared__ int hB[NBK];
  int t = threadIdx.x;
  for (int i = t; i < NBK; i += 1024) hB[i] = 0;
  __syncthreads();
  int e0 = blockIdx.x * EPB + t;
  int sv[8], dv[8], rm[8], ru[8];
#pragma unroll
  for (int k = 0; k < 8; ++k) {
    int e = e0 + k * 1024;
    if (e < NE) {
      int s = src[e], d = dst[e];
      sv[k] = s; dv[k] = d;
      rm[k] = atomicAdd(&hB[d >> BSH], 1);
      ru[k] = atomicAdd(&hB[MBK + (s >> BSH)], 1);
    } else {
      sv[k] = -1;
    }
  }
  __syncthreads();
  for (int i = t; i < NBK; i += 1024) {
    int c = hB[i];
    int base = 0;
    if (c) base = (i < MBK) ? atomicAdd(&bcur_m[i], c) : atomicAdd(&bcur_u[i - MBK], c);
    hB[i] = base;
  }
  __syncthreads();
#pragma unroll
  for (int k = 0; k < 8; ++k) {
    if (sv[k] >= 0) {
      int s = sv[k], d = dv[k];
      stage_m[hB[d >> BSH] + rm[k]] = ((unsigned)(d & 255) << 24) | (unsigned)s;
      stage_u[hB[MBK + (s >> BSH)] + ru[k]] = ((unsigned)(s & 255) << 24) | (unsigned)d;
    }
  }
}

__global__ __launch_bounds__(1024) void passB_kernel(
    const int* __restrict__ bbase_m, const int* __restrict__ bbase_u,
    const unsigned* __restrict__ stage_m, const unsigned* __restrict__ stage_u,
    int* __restrict__ csr_m, int* __restrict__ csr_u,
    int* __restrict__ rp_m, int* __restrict__ rp_u) {
  __shared__ int cnt[256];
  __shared__ int sc[256];
  int b = blockIdx.x;
  const unsigned* stage; int* csr; int* rp; int idbase, ntot, bb, be;
  if (b < MBK) {
    stage = stage_m; csr = csr_m; rp = rp_m;
    idbase = b << BSH; ntot = NM;
    bb = bbase_m[b]; be = bbase_m[b + 1];
  } else {
    int c = b - MBK;
    stage = stage_u; csr = csr_u; rp = rp_u;
    idbase = c << BSH; ntot = NU;
    bb = bbase_u[c]; be = bbase_u[c + 1];
  }
  int nloc = min(256, ntot - idbase);
  int t = threadIdx.x;
  if (t < 256) cnt[t] = 0;
  __syncthreads();
  for (int j = bb + t; j < be; j += 1024) atomicAdd(&cnt[stage[j] >> 24], 1);
  __syncthreads();
  int c0 = (t < 256) ? cnt[t] : 0;
  if (t < 256) sc[t] = c0;
  __syncthreads();
  for (int off = 1; off < 256; off <<= 1) {
    int v = 0;
    if (t < 256 && t >= off) v = sc[t - off];
    __syncthreads();
    if (t < 256) sc[t] += v;
    __syncthreads();
  }
  if (t < nloc) {
    int e = bb + sc[t] - c0;
    rp[idbase + t] = e;
    cnt[t] = e;                     // reuse as cursor
  }
  if (t == 0 && idbase + nloc == ntot) rp[ntot] = be;
  __syncthreads();
  for (int j = bb + t; j < be; j += 1024) {
    unsigned e = stage[j];
    int pos = atomicAdd(&cnt[e >> 24], 1);
    csr[pos] = (int)(e & 0xFFFFFFu);
  }
}

// ---------------- input projections / conversions ----------------

__global__ void proj_user_kernel(const float* __restrict__ xu, const float* __restrict__ Wu,
                                 const float* __restrict__ bu, unsigned short* __restrict__ hu) {
  __shared__ float Wt[FU][HD + 1];
  __shared__ float Xl[16][FU];
  int t = threadIdx.x;
  int lane = t & 63, wg = t >> 6;
  int row0 = blockIdx.x * 16;
  for (int h = wg; h < HD; h += 4)
    if (lane < FU) Wt[lane][h] = Wu[h * FU + lane];
  for (int r = wg; r < 16; r += 4)
    if (lane < FU) Xl[r][lane] = xu[(row0 + r) * FU + lane];
  __syncthreads();
  float b = bu[lane];
  float acc[4] = {0.f, 0.f, 0.f, 0.f};
  for (int k = 0; k < FU; ++k) {
    float w = Wt[k][lane];
#pragma unroll
    for (int j = 0; j < 4; ++j) acc[j] += Xl[wg * 4 + j][k] * w;
  }
#pragma unroll
  for (int j = 0; j < 4; ++j)
    hu[(row0 + wg * 4 + j) * HD + lane] = f2bf(acc[j] + b);
}

// x_user fp32 [NU][24] -> bf16 [NU][32] (cols 24..31 zero)
__global__ void convXu_kernel(const float* __restrict__ xu, unsigned short* __restrict__ xub) {
  int i = blockIdx.x * 256 + threadIdx.x;
  if (i < NU * 32) {
    int r = i >> 5, c = i & 31;
    xub[i] = (c < FU) ? f2bf(xu[r * FU + c]) : 0;
  }
}

// W_movie fp32 -> bf16 (once per launch)
__global__ void convW_kernel(const float* __restrict__ W, unsigned short* __restrict__ Wb,
                             int n) {
  int i = blockIdx.x * 256 + threadIdx.x;
  if (i < n) Wb[i] = f2bf(W[i]);
}

// [Wl | Wr] -> bf16 Wb2[h][128]  (k<64 from Wl, k>=64 from Wr)
__global__ void convW2_kernel(const float* __restrict__ Wl, const float* __restrict__ Wr,
                              unsigned short* __restrict__ Wb2) {
  int i = blockIdx.x * 256 + threadIdx.x;
  if (i < HD * 128) {
    int h = i >> 7, k = i & 127;
    float v = (k < 64) ? Wl[h * 64 + k] : Wr[h * 64 + (k - 64)];
    Wb2[i] = f2bf(v);
  }
}

// Wum96[h][96]: k<24 = (Wl1_um @ W_user)[h][k]; k==31 = (Wl1_um @ b_user)[h];
// k in 32..95 = Wr1_um[h][k-32]; else 0.
__global__ void convWum_kernel(const float* __restrict__ Wl, const float* __restrict__ Wu,
                               const float* __restrict__ bu, const float* __restrict__ Wr,
                               unsigned short* __restrict__ W96) {
  int i = blockIdx.x * 256 + threadIdx.x;
  if (i >= 64 * 96) return;
  int h = i / 96, k = i - h * 96;
  float v = 0.f;
  if (k < FU) {
    for (int j = 0; j < 64; ++j) v += Wl[h * 64 + j] * Wu[j * FU + k];
  } else if (k == 31) {
    for (int j = 0; j < 64; ++j) v += Wl[h * 64 + j] * bu[j];
  } else if (k >= 32) {
    v = Wr[h * 64 + (k - 32)];
  }
  W96[i] = f2bf(v);
}

// Movie projection via MFMA (verified config).
__global__ __launch_bounds__(256) void proj_movie_kernel(
    const float* __restrict__ xm, const unsigned short* __restrict__ Wb,
    const float* __restrict__ bm, unsigned short* __restrict__ hm) {
  __shared__ unsigned short Xs[64][72];
  __shared__ unsigned short Ws[64][72];
  int t = threadIdx.x;
  int lane = t & 63, wid = t >> 6;
  int row0 = blockIdx.x * 64;
  int r0 = wid * 16;
  f32x4 acc[4];
#pragma unroll
  for (int nt = 0; nt < 4; ++nt) acc[nt] = (f32x4){0.f, 0.f, 0.f, 0.f};

  for (int k0 = 0; k0 < 448; k0 += 64) {
    int kc = min(64, FM - k0);
    __syncthreads();
    for (int i = t; i < 1024; i += 256) {
      int r = i >> 4, c4 = i & 15;
      float4 v = make_float4(0.f, 0.f, 0.f, 0.f);
      if (c4 * 4 < kc && row0 + r < NM)
        v = *(const float4*)(xm + (size_t)(row0 + r) * FM + k0 + c4 * 4);
      ushort4 o;
      o.x = f2bf(v.x); o.y = f2bf(v.y); o.z = f2bf(v.z); o.w = f2bf(v.w);
      *(ushort4*)&Xs[r][c4 * 4] = o;
    }
    for (int i = t; i < 1024; i += 256) {
      int h = i >> 4, c4 = i & 15;
      uint2 v = make_uint2(0u, 0u);
      if (c4 * 4 < kc)
        v = *(const uint2*)(Wb + (size_t)h * FM + k0 + c4 * 4);
      *(uint2*)&Ws[h][c4 * 4] = v;
    }
    __syncthreads();
#pragma unroll
    for (int kk = 0; kk < 64; kk += 32) {
      bf16x8 a = *(const bf16x8*)&Xs[r0 + (lane & 15)][kk + (lane >> 4) * 8];
#pragma unroll
      for (int nt = 0; nt < 4; ++nt) {
        bf16x8 b = *(const bf16x8*)&Ws[nt * 16 + (lane & 15)][kk + (lane >> 4) * 8];
        acc[nt] = __builtin_amdgcn_mfma_f32_16x16x32_bf16(a, b, acc[nt], 0, 0, 0);
      }
    }
  }
  int col = lane & 15;
  int rbase = r0 + (lane >> 4) * 4;
#pragma unroll
  for (int nt = 0; nt < 4; ++nt) {
    float b = bm[nt * 16 + col];
#pragma unroll
    for (int j = 0; j < 4; ++j) {
      int row = row0 + rbase + j;
      if (row < NM)
        hm[(size_t)row * HD + nt * 16 + col] = f2bf(acc[nt][j] + b);
    }
  }
}

// ---------------- movie-side aggregation in 24-dim space -------------------
// Gathers xub rows (64B) over csr_m; out a24[NM][32] bf16, col31 = deg flag.

__global__ __launch_bounds__(256) void agg24_kernel(
    const unsigned short* __restrict__ xub, const int* __restrict__ rp,
    const int* __restrict__ csr, unsigned short* __restrict__ a24, int n) {
  int wid = threadIdx.x >> 6, lane = threadIdx.x & 63;
  int row = blockIdx.x * 4 + wid;
  if (row >= n) return;
  int beg = rp[row], end = rp[row + 1];
  int g = lane >> 3;       // neighbor slot 0..7
  int fq = lane & 7;       // quad of 4 bf16 (8B), 8 quads = 32 elems
  float a0 = 0.f, a1 = 0.f, a2 = 0.f, a3 = 0.f;
  int i = beg;
  for (; i + 16 <= end; i += 16) {
    int n0 = csr[i + g];
    int n1 = csr[i + 8 + g];
    uint2 v0 = *(const uint2*)(xub + (size_t)n0 * 32 + fq * 4);
    uint2 v1 = *(const uint2*)(xub + (size_t)n1 * 32 + fq * 4);
    float2 p0 = unpk(v0.x), p1 = unpk(v0.y);
    float2 q0 = unpk(v1.x), q1 = unpk(v1.y);
    a0 += p0.x + q0.x; a1 += p0.y + q0.y;
    a2 += p1.x + q1.x; a3 += p1.y + q1.y;
  }
  for (; i < end; i += 8) {
    int idx = i + g;
    if (idx < end) {
      int nb = csr[idx];
      uint2 v = *(const uint2*)(xub + (size_t)nb * 32 + fq * 4);
      float2 p0 = unpk(v.x), p1 = unpk(v.y);
      a0 += p0.x; a1 += p0.y; a2 += p1.x; a3 += p1.y;
    }
  }
  a0 += __shfl_xor(a0, 8); a0 += __shfl_xor(a0, 16); a0 += __shfl_xor(a0, 32);
  a1 += __shfl_xor(a1, 8); a1 += __shfl_xor(a1, 16); a1 += __shfl_xor(a1, 32);
  a2 += __shfl_xor(a2, 8); a2 += __shfl_xor(a2, 16); a2 += __shfl_xor(a2, 32);
  a3 += __shfl_xor(a3, 8); a3 += __shfl_xor(a3, 16); a3 += __shfl_xor(a3, 32);
  if (g == 0) {
    float inv = 1.0f / fmaxf((float)(end - beg), 1.0f);
    ushort4 o;
    o.x = f2bf(a0 * inv); o.y = f2bf(a1 * inv);
    o.z = f2bf(a2 * inv); o.w = f2bf(a3 * inv);
    if (fq == 7) o.w = (end > beg) ? 0x3F80 : 0;   // col31: bf16(1.0) flag
    *(ushort4*)(a24 + (size_t)row * 32 + fq * 4) = o;
  }
}

// ---------------- user-side mean aggregation (bf16 out) --------------------

__global__ __launch_bounds__(256) void agg_mean_kernel(
    const unsigned short* __restrict__ table, const int* __restrict__ rp,
    const int* __restrict__ csr, unsigned short* __restrict__ out, int n) {
  int wid = threadIdx.x >> 6;
  int lane = threadIdx.x & 63;
  int row = blockIdx.x * 4 + wid;
  if (row >= n) return;
  int beg = rp[row], end = rp[row + 1];
  int g = lane >> 4;        // neighbor slot 0..3
  int fq = lane & 15;       // feature quad
  float a0 = 0.f, a1 = 0.f, a2 = 0.f, a3 = 0.f;
  int i = beg;
  for (; i + 16 <= end; i += 16) {
    int n0 = csr[i + g];
    int n1 = csr[i + 4 + g];
    int n2 = csr[i + 8 + g];
    int n3 = csr[i + 12 + g];
    uint2 v0 = *(const uint2*)(table + (size_t)n0 * HD + fq * 4);
    uint2 v1 = *(const uint2*)(table + (size_t)n1 * HD + fq * 4);
    uint2 v2 = *(const uint2*)(table + (size_t)n2 * HD + fq * 4);
    uint2 v3 = *(const uint2*)(table + (size_t)n3 * HD + fq * 4);
    float2 p0 = unpk(v0.x), p1 = unpk(v0.y);
    float2 q0 = unpk(v1.x), q1 = unpk(v1.y);
    float2 r0 = unpk(v2.x), r1 = unpk(v2.y);
    float2 s0 = unpk(v3.x), s1 = unpk(v3.y);
    a0 += (p0.x + q0.x) + (r0.x + s0.x);
    a1 += (p0.y + q0.y) + (r0.y + s0.y);
    a2 += (p1.x + q1.x) + (r1.x + s1.x);
    a3 += (p1.y + q1.y) + (r1.y + s1.y);
  }
  for (; i + 8 <= end; i += 8) {
    int n0 = csr[i + g];
    int n1 = csr[i + 4 + g];
    uint2 v0 = *(const uint2*)(table + (size_t)n0 * HD + fq * 4);
    uint2 v1 = *(const uint2*)(table + (size_t)n1 * HD + fq * 4);
    float2 p0 = unpk(v0.x), p1 = unpk(v0.y);
    float2 q0 = unpk(v1.x), q1 = unpk(v1.y);
    a0 += p0.x + q0.x; a1 += p0.y + q0.y;
    a2 += p1.x + q1.x; a3 += p1.y + q1.y;
  }
  for (; i < end; i += 4) {
    int idx = i + g;
    if (idx < end) {
      int nb = csr[idx];
      uint2 v = *(const uint2*)(table + (size_t)nb * HD + fq * 4);
      float2 p0 = unpk(v.x), p1 = unpk(v.y);
      a0 += p0.x; a1 += p0.y; a2 += p1.x; a3 += p1.y;
    }
  }
  a0 += __shfl_xor(a0, 16); a0 += __shfl_xor(a0, 32);
  a1 += __shfl_xor(a1, 16); a1 += __shfl_xor(a1, 32);
  a2 += __shfl_xor(a2, 16); a2 += __shfl_xor(a2, 32);
  a3 += __shfl_xor(a3, 16); a3 += __shfl_xor(a3, 32);
  float inv = 1.0f / fmaxf((float)(end - beg), 1.0f);
  if (lane < 16) {
    ushort4 o;
    o.x = f2bf(a0 * inv); o.y = f2bf(a1 * inv);
    o.z = f2bf(a2 * inv); o.w = f2bf(a3 * inv);
    *(ushort4*)(out + (size_t)row * HD + fq * 4) = o;
  }
}

// ---------------- SAGE linear via MFMA, K=128 (user side) ------------------

template <int OUTBF>
__global__ __launch_bounds__(256) void sage64_kernel(
    const unsigned short* __restrict__ agg, const unsigned short* __restrict__ xd,
    const unsigned short* __restrict__ Wb2, const float* __restrict__ bl,
    void* __restrict__ outp, int n) {
  __shared__ unsigned short Xs[64][136];
  __shared__ unsigned short Ws[64][136];
  int t = threadIdx.x;
  int lane = t & 63, wid = t >> 6;
  int row0 = blockIdx.x * 64;
  int r0 = wid * 16;
  for (int i = t; i < 1024; i += 256) {
    int h = i >> 4, g = i & 15;
    *(uint4*)&Ws[h][g * 8] = *(const uint4*)(Wb2 + (size_t)h * 128 + g * 8);
  }
  for (int i = t; i < 1024; i += 256) {
    int r = i >> 4, g = i & 15;
    uint4 v = make_uint4(0u, 0u, 0u, 0u);
    if (row0 + r < n) {
      if (g < 8) v = *(const uint4*)(agg + (size_t)(row0 + r) * HD + g * 8);
      else       v = *(const uint4*)(xd + (size_t)(row0 + r) * HD + (g - 8) * 8);
    }
    *(uint4*)&Xs[r][g * 8] = v;
  }
  __syncthreads();
  f32x4 acc[4];
#pragma unroll
  for (int nt = 0; nt < 4; ++nt) acc[nt] = (f32x4){0.f, 0.f, 0.f, 0.f};
#pragma unroll
  for (int kk = 0; kk < 128; kk += 32) {
    bf16x8 a = *(const bf16x8*)&Xs[r0 + (lane & 15)][kk + (lane >> 4) * 8];
#pragma unroll
    for (int nt = 0; nt < 4; ++nt) {
      bf16x8 b = *(const bf16x8*)&Ws[nt * 16 + (lane & 15)][kk + (lane >> 4) * 8];
      acc[nt] = __builtin_amdgcn_mfma_f32_16x16x32_bf16(a, b, acc[nt], 0, 0, 0);
    }
  }
  int col = lane & 15;
  int rbase = r0 + (lane >> 4) * 4;
#pragma unroll
  for (int nt = 0; nt < 4; ++nt) {
    float b = bl[nt * 16 + col];
#pragma unroll
    for (int j = 0; j < 4; ++j) {
      int row = row0 + rbase + j;
      if (row < n) {
        float v = fmaxf(acc[nt][j] + b, 0.f);
        if (OUTBF) ((unsigned short*)outp)[(size_t)row * HD + nt * 16 + col] = f2bf(v);
        else       ((float*)outp)[(size_t)row * HD + nt * 16 + col] = v;
      }
    }
  }
}

// ---------------- SAGE linear via MFMA, K=96 (movie side, folded proj) -----
// X = [a24 (32, incl. flag col31) | hm (64)], W = Wum96[64][96].

__global__ __launch_bounds__(256) void sage_um_kernel(
    const unsigned short* __restrict__ a24, const unsigned short* __restrict__ hm,
    const unsigned short* __restrict__ W96, const float* __restrict__ bl,
    unsigned short* __restrict__ m1, int n) {
  __shared__ unsigned short Xs[64][104];   // 104 shorts = 208B = 13x16B
  __shared__ unsigned short Ws[64][104];
  int t = threadIdx.x;
  int lane = t & 63, wid = t >> 6;
  int row0 = blockIdx.x * 64;
  int r0 = wid * 16;
  for (int i = t; i < 768; i += 256) {
    int h = i / 12, g = i - h * 12;
    *(uint4*)&Ws[h][g * 8] = *(const uint4*)(W96 + (size_t)h * 96 + g * 8);
  }
  for (int i = t; i < 768; i += 256) {
    int r = i / 12, g = i - r * 12;
    uint4 v = make_uint4(0u, 0u, 0u, 0u);
    if (row0 + r < n) {
      if (g < 4) v = *(const uint4*)(a24 + (size_t)(row0 + r) * 32 + g * 8);
      else       v = *(const uint4*)(hm + (size_t)(row0 + r) * HD + (g - 4) * 8);
    }
    *(uint4*)&Xs[r][g * 8] = v;
  }
  __syncthreads();
  f32x4 acc[4];
#pragma unroll
  for (int nt = 0; nt < 4; ++nt) acc[nt] = (f32x4){0.f, 0.f, 0.f, 0.f};
#pragma unroll
  for (int kk = 0; kk < 96; kk += 32) {
    bf16x8 a = *(const bf16x8*)&Xs[r0 + (lane & 15)][kk + (lane >> 4) * 8];
#pragma unroll
    for (int nt = 0; nt < 4; ++nt) {
      bf16x8 b = *(const bf16x8*)&Ws[nt * 16 + (lane & 15)][kk + (lane >> 4) * 8];
      acc[nt] = __builtin_amdgcn_mfma_f32_16x16x32_bf16(a, b, acc[nt], 0, 0, 0);
    }
  }
  int col = lane & 15;
  int rbase = r0 + (lane >> 4) * 4;
#pragma unroll
  for (int nt = 0; nt < 4; ++nt) {
    float b = bl[nt * 16 + col];
#pragma unroll
    for (int j = 0; j < 4; ++j) {
      int row = row0 + rbase + j;
      if (row < n)
        m1[(size_t)row * HD + nt * 16 + col] = f2bf(fmaxf(acc[nt][j] + b, 0.f));
    }
  }
}

// ---------------- layer 2 (z-trick) ----------------

__global__ __launch_bounds__(256) void zproj_kernel(
    const unsigned short* __restrict__ u1, const float* __restrict__ Wl2,
    float4* __restrict__ z) {
  __shared__ float W[3][64];
  int t = threadIdx.x;
  if (t < 192) W[t / 64][t & 63] = Wl2[t];
  __syncthreads();
  int wid = t >> 6, lane = t & 63;
  int g = lane >> 4, fq = lane & 15;
  int row = blockIdx.x * 16 + wid * 4 + g;
  if (row >= NU) return;
  uint2 v = *(const uint2*)(u1 + (size_t)row * HD + fq * 4);
  float2 p0 = unpk(v.x), p1 = unpk(v.y);
  int f = fq * 4;
  float z0 = p0.x * W[0][f] + p0.y * W[0][f + 1] + p1.x * W[0][f + 2] + p1.y * W[0][f + 3];
  float z1 = p0.x * W[1][f] + p0.y * W[1][f + 1] + p1.x * W[1][f + 2] + p1.y * W[1][f + 3];
  float z2 = p0.x * W[2][f] + p0.y * W[2][f + 1] + p1.x * W[2][f + 2] + p1.y * W[2][f + 3];
#pragma unroll
  for (int off = 1; off < 16; off <<= 1) {
    z0 += __shfl_xor(z0, off);
    z1 += __shfl_xor(z1, off);
    z2 += __shfl_xor(z2, off);
  }
  if (fq == 0) z[row] = make_float4(z0, z1, z2, 0.f);
}

__global__ __launch_bounds__(256) void agg4_kernel(
    const float4* __restrict__ z, const int* __restrict__ rp,
    const int* __restrict__ csr, float4* __restrict__ zagg, int n) {
  int wid = threadIdx.x >> 6, lane = threadIdx.x & 63;
  int row = blockIdx.x * 4 + wid;
  if (row >= n) return;
  int beg = rp[row], end = rp[row + 1];
  float s0 = 0.f, s1 = 0.f, s2 = 0.f;
  for (int i = beg + lane; i < end; i += 64) {
    float4 v = z[csr[i]];
    s0 += v.x; s1 += v.y; s2 += v.z;
  }
#pragma unroll
  for (int off = 1; off < 64; off <<= 1) {
    s0 += __shfl_xor(s0, off);
    s1 += __shfl_xor(s1, off);
    s2 += __shfl_xor(s2, off);
  }
  if (lane == 0) {
    float inv = 1.0f / fmaxf((float)(end - beg), 1.0f);
    zagg[row] = make_float4(s0 * inv, s1 * inv, s2 * inv, 0.f);
  }
}

// out2: out[m][g] = zagg[m][g] + bl2[g] + m1[m] . Wr2[g]   (m1 bf16)
__global__ void out2_kernel(const float4* __restrict__ zagg,
                            const unsigned short* __restrict__ m1,
                            const float* __restrict__ Wr2, const float* __restrict__ bl2,
                            float* __restrict__ out, int n) {
  int wid = threadIdx.x >> 6, lane = threadIdx.x & 63;
  int row = blockIdx.x * 4 + wid;
  if (row >= n) return;
  float mm = bf2f(m1[(size_t)row * HD + lane]);
  float4 za = zagg[row];
  float zc[3] = {za.x, za.y, za.z};
#pragma unroll
  for (int g = 0; g < 3; ++g) {
    float p = mm * Wr2[g * HD + lane];
#pragma unroll
    for (int off = 32; off > 0; off >>= 1) p += __shfl_down(p, off);
    if (lane == 0) out[row * 3 + g] = p + zc[g] + bl2[g];
  }
}

// ---------------------------------------------------------------------------

extern "C" void kernel_launch(void* const* d_in, const int* in_sizes, int n_in,
                              void* d_out, int out_size, void* d_ws, size_t ws_size,
                              hipStream_t stream) {
  const float* x_user  = (const float*)d_in[0];
  const float* x_movie = (const float*)d_in[1];
  const int*   e_src   = (const int*)d_in[2];
  const int*   e_dst   = (const int*)d_in[3];
  const float* W_user  = (const float*)d_in[4];
  const float* b_user  = (const float*)d_in[5];
  const float* W_movie = (const float*)d_in[6];
  const float* b_movie = (const float*)d_in[7];
  const float* Wl1_um  = (const float*)d_in[8];
  const float* bl1_um  = (const float*)d_in[9];
  const float* Wr1_um  = (const float*)d_in[10];
  const float* Wl1_mu  = (const float*)d_in[11];
  const float* bl1_mu  = (const float*)d_in[12];
  const float* Wr1_mu  = (const float*)d_in[13];
  const float* Wl2_um  = (const float*)d_in[14];
  const float* bl2_um  = (const float*)d_in[15];
  const float* Wr2_um  = (const float*)d_in[16];
  float* outp = (float*)d_out;

  // ---- workspace carve-up ----
  char* p = (char*)d_ws;
  size_t off = 0;
  auto take = [&](size_t bytes) { void* r = p + off; off += alignup(bytes); return r; };

  int* rp_m    = (int*)take(size_t(NM + 1) * 4);
  int* rp_u    = (int*)take(size_t(NU + 1) * 4);
  int* bh      = (int*)take(size_t(NBK) * 4);
  int* bbase_m = (int*)take(size_t(MBK + 1) * 4);
  int* bbase_u = (int*)take(size_t(UBK + 1) * 4);
  int* bcur_m  = (int*)take(size_t(MBK) * 4);
  int* bcur_u  = (int*)take(size_t(UBK) * 4);
  int* csr_m   = (int*)take(size_t(NE) * 4);
  int* csr_u   = (int*)take(size_t(NE) * 4);

  // overlay: staging (build phase) aliases feature buffers (feature phase)
  size_t ov_base = off;
  unsigned* stage_m = (unsigned*)take(size_t(NE) * 4);
  unsigned* stage_u = (unsigned*)take(size_t(NE) * 4);
  size_t stage_end = off;
  off = ov_base;
  unsigned short* hu   = (unsigned short*)take(size_t(NU) * HD * 2);
  unsigned short* hm   = (unsigned short*)take(size_t(NM) * HD * 2);
  unsigned short* u1   = (unsigned short*)take(size_t(NU) * HD * 2);
  unsigned short* m1   = (unsigned short*)take(size_t(NM) * HD * 2);
  unsigned short* aggb = (unsigned short*)take(size_t(NU) * HD * 2);
  unsigned short* xub  = (unsigned short*)take(size_t(NU) * 32 * 2);
  unsigned short* a24  = (unsigned short*)take(size_t(NM) * 32 * 2);
  if (off < stage_end) off = stage_end;
  float4* z    = (float4*)take(size_t(NU) * 16);
  float4* zagg = (float4*)take(size_t(NM) * 16);
  unsigned short* Wb    = (unsigned short*)take(size_t(HD) * FM * 2);
  unsigned short* Wmu   = (unsigned short*)take(size_t(HD) * 128 * 2);
  unsigned short* Wum96 = (unsigned short*)take(size_t(HD) * 96 * 2);
  if (off > ws_size) return;

  const int TB = 256;

  // ---- CSR build ----
  hipMemsetAsync(bh, 0, size_t(NBK) * 4, stream);
  histB_kernel<<<512, 256, 0, stream>>>(e_src, e_dst, bh);
  scanB_kernel<<<1, 1024, 0, stream>>>(bh, bbase_m, bbase_u, bcur_m, bcur_u);
  passA_kernel<<<(NE + EPB - 1) / EPB, 1024, 0, stream>>>(e_src, e_dst, bcur_m, bcur_u,
                                                          stage_m, stage_u);
  passB_kernel<<<NBK, 1024, 0, stream>>>(bbase_m, bbase_u, stage_m, stage_u,
                                         csr_m, csr_u, rp_m, rp_u);

  // ---- projections + conversions ----
  convW_kernel<<<(HD * FM + 255) / 256, 256, 0, stream>>>(W_movie, Wb, HD * FM);
  convW2_kernel<<<(HD * 128 + 255) / 256, 256, 0, stream>>>(Wl1_mu, Wr1_mu, Wmu);
  convWum_kernel<<<(64 * 96 + 255) / 256, 256, 0, stream>>>(Wl1_um, W_user, b_user,
                                                            Wr1_um, Wum96);
  convXu_kernel<<<(NU * 32 + 255) / 256, 256, 0, stream>>>(x_user, xub);
  proj_user_kernel<<<NU / 16, TB, 0, stream>>>(x_user, W_user, b_user, hu);
  proj_movie_kernel<<<(NM + 63) / 64, TB, 0, stream>>>(x_movie, Wb, b_movie, hm);

  // ---- layer 1: movie side (24-dim aggregation + folded projection) ----
  agg24_kernel<<<(NM + 3) / 4, TB, 0, stream>>>(xub, rp_m, csr_m, a24, NM);
  sage_um_kernel<<<(NM + 63) / 64, TB, 0, stream>>>(a24, hm, Wum96, bl1_um, m1, NM);

  // ---- layer 1: user side ----
  agg_mean_kernel<<<(NU + 3) / 4, TB, 0, stream>>>(hm, rp_u, csr_u, aggb, NU);
  sage64_kernel<1><<<(NU + 63) / 64, TB, 0, stream>>>(aggb, hu, Wmu, bl1_mu, u1, NU);

  // ---- layer 2 (z-trick) ----
  zproj_kernel<<<(NU + 15) / 16, TB, 0, stream>>>(u1, Wl2_um, z);
  agg4_kernel<<<(NM + 3) / 4, TB, 0, stream>>>(z, rp_m, csr_m, zagg, NM);
  out2_kernel<<<(NM + 3) / 4, TB, 0, stream>>>(zagg, m1, Wr2_um, bl2_um, outp, NM);
}

// Round 14
// 363.763 us; speedup vs baseline: 1.2554x; 1.0523x over previous
//
#include <hip/hip_runtime.h>

// ---------------------------------------------------------------------------
// Hetero GraphSAGE (user<->movie). LDS-binned bucketed CSR build, fp8 gather
// tables (per-XCD-L2-resident), MFMA GEMMs, folded projections, z-trick.
// ---------------------------------------------------------------------------

constexpr int NU = 100000;   // users
constexpr int NM = 50000;    // movies
constexpr int NE = 4000000;  // edges
constexpr int FU = 24;       // user feat
constexpr int FM = 404;      // movie feat
constexpr int HD = 64;       // hidden

constexpr int BSH = 8;                       // bucket = 256 node ids
constexpr int MBK = (NM + 255) >> BSH;       // 196 movie buckets
constexpr int UBK = (NU + 255) >> BSH;       // 391 user buckets
constexpr int NBK = MBK + UBK;               // 587
constexpr int EPB = 8192;                    // edges per passA block (1024 thr x 8)

static inline size_t alignup(size_t x) { return (x + 255) & ~size_t(255); }

__device__ __forceinline__ float bf2f(unsigned short h) {
  return __uint_as_float(((unsigned int)h) << 16);
}
__device__ __forceinline__ unsigned short f2bf(float f) {
  unsigned int u = __float_as_uint(f);
  u = (u + 0x7FFFu + ((u >> 16) & 1u)) >> 16;   // RNE
  return (unsigned short)u;
}
__device__ __forceinline__ float2 unpk(unsigned u) {
  return make_float2(__uint_as_float(u << 16), __uint_as_float(u & 0xFFFF0000u));
}
// fp8 e4m3fn decode (low 8 bits of v): 3 VALU ops
__device__ __forceinline__ float fp8dec(unsigned v) {
  unsigned u = ((v & 0x80u) << 24) | ((v & 0x7Fu) << 20);
  return __uint_as_float(u) * 0x1p120f;
}
// fp8 e4m3fn encode, RNE, clamp to +-448
__device__ __forceinline__ unsigned char f2fp8(float f) {
  float a = fminf(fabsf(f), 448.0f);
  unsigned u = __float_as_uint(a * 0x1p-120f);
  u = u + 0x7FFFFu + ((u >> 20) & 1u);
  return (unsigned char)(((u >> 20) & 0x7Fu) | ((__float_as_uint(f) >> 24) & 0x80u));
}

using bf16x8 = __attribute__((ext_vector_type(8))) short;   // 8 bf16 = 4 VGPRs
using f32x4  = __attribute__((ext_vector_type(4))) float;   // MFMA C/D frag

// ---------------- CSR build ----------------

__global__ __launch_bounds__(256) void histB_kernel(const int* __restrict__ src,
                                                    const int* __restrict__ dst,
                                                    int* __restrict__ bh) {
  __shared__ int h[NBK];
  for (int i = threadIdx.x; i < NBK; i += 256) h[i] = 0;
  __syncthreads();
  int idx = blockIdx.x * 256 + threadIdx.x;
  int stride = gridDim.x * 256;
  for (int i = idx; i < NE; i += stride) {
    atomicAdd(&h[dst[i] >> BSH], 1);
    atomicAdd(&h[MBK + (src[i] >> BSH)], 1);
  }
  __syncthreads();
  for (int i = threadIdx.x; i < NBK; i += 256) {
    int c = h[i];
    if (c) atomicAdd(&bh[i], c);
  }
}

__global__ __launch_bounds__(1024) void scanB_kernel(const int* __restrict__ bh,
                                                     int* __restrict__ bbase_m,
                                                     int* __restrict__ bbase_u,
                                                     int* __restrict__ bcur_m,
                                                     int* __restrict__ bcur_u) {
  __shared__ int tmp[1024];
  int t = threadIdx.x;
  int vm = (t < MBK) ? bh[t] : 0;
  tmp[t] = vm;
  __syncthreads();
  for (int off = 1; off < 1024; off <<= 1) {
    int v = (t >= off) ? tmp[t - off] : 0;
    __syncthreads();
    tmp[t] += v;
    __syncthreads();
  }
  if (t < MBK) {
    int e = tmp[t] - vm;
    bbase_m[t] = e; bcur_m[t] = e;
    if (t == MBK - 1) bbase_m[MBK] = tmp[t];
  }
  __syncthreads();
  int vu = (t < UBK) ? bh[MBK + t] : 0;
  tmp[t] = vu;
  __syncthreads();
  for (int off = 1; off < 1024; off <<= 1) {
    int v = (t >= off) ? tmp[t - off] : 0;
    __syncthreads();
    tmp[t] += v;
    __syncthreads();
  }
  if (t < UBK) {
    int e = tmp[t] - vu;
    bbase_u[t] = e; bcur_u[t] = e;
    if (t == UBK - 1) bbase_u[UBK] = tmp[t];
  }
}

// Pass A with LDS binning: rank -> scatter into LDS bins -> one reservation
// atomic per (block,bucket) -> wave-per-bucket contiguous copy-out.
__global__ __launch_bounds__(1024) void passA_kernel(
    const int* __restrict__ src, const int* __restrict__ dst,
    int* __restrict__ bcur_m, int* __restrict__ bcur_u,
    unsigned* __restrict__ stage_m, unsigned* __restrict__ stage_u) {
  __shared__ int hB[NBK];          // counts -> local offsets
  __shared__ int cntB[NBK];
  __shared__ int gB[NBK];          // global base - local base
  __shared__ int tmp[1024];
  __shared__ unsigned binM[EPB];   // 32 KB
  __shared__ unsigned binU[EPB];   // 32 KB
  int t = threadIdx.x;
  for (int i = t; i < NBK; i += 1024) hB[i] = 0;
  __syncthreads();
  int e0 = blockIdx.x * EPB + t;
  int sv[8], dv[8], rm[8], ru[8];
#pragma unroll
  for (int k = 0; k < 8; ++k) {
    int e = e0 + k * 1024;
    if (e < NE) {
      int s = src[e], d = dst[e];
      sv[k] = s; dv[k] = d;
      rm[k] = atomicAdd(&hB[d >> BSH], 1);
      ru[k] = atomicAdd(&hB[MBK + (s >> BSH)], 1);
    } else {
      sv[k] = -1;
    }
  }
  __syncthreads();
  // scan M segment
  int cm = (t < MBK) ? hB[t] : 0;
  tmp[t] = cm;
  __syncthreads();
  for (int off = 1; off < 1024; off <<= 1) {
    int v = (t >= off) ? tmp[t - off] : 0;
    __syncthreads();
    tmp[t] += v;
    __syncthreads();
  }
  int lofsM = tmp[t] - cm;
  __syncthreads();
  // scan U segment
  int cu_ = (t < UBK) ? hB[MBK + t] : 0;
  tmp[t] = cu_;
  __syncthreads();
  for (int off = 1; off < 1024; off <<= 1) {
    int v = (t >= off) ? tmp[t - off] : 0;
    __syncthreads();
    tmp[t] += v;
    __syncthreads();
  }
  int lofsU = tmp[t] - cu_;
  __syncthreads();
  if (t < MBK) { cntB[t] = cm; hB[t] = lofsM; }
  if (t < UBK) { cntB[MBK + t] = cu_; hB[MBK + t] = lofsU; }
  __syncthreads();
  // scatter into LDS bins
#pragma unroll
  for (int k = 0; k < 8; ++k) {
    if (sv[k] >= 0) {
      int s = sv[k], d = dv[k];
      binM[hB[d >> BSH] + rm[k]] = ((unsigned)(d & 255) << 24) | (unsigned)s;
      binU[hB[MBK + (s >> BSH)] + ru[k]] = ((unsigned)(s & 255) << 24) | (unsigned)d;
    }
  }
  __syncthreads();
  // reserve global spans
  for (int b = t; b < NBK; b += 1024) {
    int cc = cntB[b];
    if (cc) {
      int gb = (b < MBK) ? atomicAdd(&bcur_m[b], cc) : atomicAdd(&bcur_u[b - MBK], cc);
      gB[b] = gb - hB[b];
    }
  }
  __syncthreads();
  // wave-per-bucket contiguous copy-out
  int wv = t >> 6, ln = t & 63;
  for (int b = wv; b < MBK; b += 16) {
    int cc = cntB[b], lo = hB[b], go = hB[b] + gB[b];
    for (int j = ln; j < cc; j += 64) stage_m[go + j] = binM[lo + j];
  }
  for (int b = wv; b < UBK; b += 16) {
    int cc = cntB[MBK + b], lo = hB[MBK + b], go = hB[MBK + b] + gB[MBK + b];
    for (int j = ln; j < cc; j += 64) stage_u[go + j] = binU[lo + j];
  }
}

__global__ __launch_bounds__(1024) void passB_kernel(
    const int* __restrict__ bbase_m, const int* __restrict__ bbase_u,
    const unsigned* __restrict__ stage_m, const unsigned* __restrict__ stage_u,
    int* __restrict__ csr_m, int* __restrict__ csr_u,
    int* __restrict__ rp_m, int* __restrict__ rp_u) {
  __shared__ int cnt[256];
  __shared__ int sc[256];
  int b = blockIdx.x;
  const unsigned* stage; int* csr; int* rp; int idbase, ntot, bb, be;
  if (b < MBK) {
    stage = stage_m; csr = csr_m; rp = rp_m;
    idbase = b << BSH; ntot = NM;
    bb = bbase_m[b]; be = bbase_m[b + 1];
  } else {
    int c = b - MBK;
    stage = stage_u; csr = csr_u; rp = rp_u;
    idbase = c << BSH; ntot = NU;
    bb = bbase_u[c]; be = bbase_u[c + 1];
  }
  int nloc = min(256, ntot - idbase);
  int t = threadIdx.x;
  if (t < 256) cnt[t] = 0;
  __syncthreads();
  for (int j = bb + t; j < be; j += 1024) atomicAdd(&cnt[stage[j] >> 24], 1);
  __syncthreads();
  int c0 = (t < 256) ? cnt[t] : 0;
  if (t < 256) sc[t] = c0;
  __syncthreads();
  for (int off = 1; off < 256; off <<= 1) {
    int v = 0;
    if (t < 256 && t >= off) v = sc[t - off];
    __syncthreads();
    if (t < 256) sc[t] += v;
    __syncthreads();
  }
  if (t < nloc) {
    int e = bb + sc[t] - c0;
    rp[idbase + t] = e;
    cnt[t] = e;                     // reuse as cursor
  }
  if (t == 0 && idbase + nloc == ntot) rp[ntot] = be;
  __syncthreads();
  for (int j = bb + t; j < be; j += 1024) {
    unsigned e = stage[j];
    int pos = atomicAdd(&cnt[e >> 24], 1);
    csr[pos] = (int)(e & 0xFFFFFFu);
  }
}

// ---------------- input projections / conversions ----------------

__global__ void proj_user_kernel(const float* __restrict__ xu, const float* __restrict__ Wu,
                                 const float* __restrict__ bu, unsigned short* __restrict__ hu) {
  __shared__ float Wt[FU][HD + 1];
  __shared__ float Xl[16][FU];
  int t = threadIdx.x;
  int lane = t & 63, wg = t >> 6;
  int row0 = blockIdx.x * 16;
  for (int h = wg; h < HD; h += 4)
    if (lane < FU) Wt[lane][h] = Wu[h * FU + lane];
  for (int r = wg; r < 16; r += 4)
    if (lane < FU) Xl[r][lane] = xu[(row0 + r) * FU + lane];
  __syncthreads();
  float b = bu[lane];
  float acc[4] = {0.f, 0.f, 0.f, 0.f};
  for (int k = 0; k < FU; ++k) {
    float w = Wt[k][lane];
#pragma unroll
    for (int j = 0; j < 4; ++j) acc[j] += Xl[wg * 4 + j][k] * w;
  }
#pragma unroll
  for (int j = 0; j < 4; ++j)
    hu[(row0 + wg * 4 + j) * HD + lane] = f2bf(acc[j] + b);
}

// x_user fp32 [NU][24] -> fp8 [NU][32] (cols 24..31 zero)
__global__ void convXu_kernel(const float* __restrict__ xu, unsigned char* __restrict__ xu8) {
  int i = blockIdx.x * 256 + threadIdx.x;
  if (i < NU * 32) {
    int r = i >> 5, c = i & 31;
    xu8[i] = (c < FU) ? f2fp8(xu[r * FU + c]) : 0;
  }
}

// W_movie fp32 -> bf16 (once per launch)
__global__ void convW_kernel(const float* __restrict__ W, unsigned short* __restrict__ Wb,
                             int n) {
  int i = blockIdx.x * 256 + threadIdx.x;
  if (i < n) Wb[i] = f2bf(W[i]);
}

// [Wl | Wr] -> bf16 Wb2[h][128]
__global__ void convW2_kernel(const float* __restrict__ Wl, const float* __restrict__ Wr,
                              unsigned short* __restrict__ Wb2) {
  int i = blockIdx.x * 256 + threadIdx.x;
  if (i < HD * 128) {
    int h = i >> 7, k = i & 127;
    float v = (k < 64) ? Wl[h * 64 + k] : Wr[h * 64 + (k - 64)];
    Wb2[i] = f2bf(v);
  }
}

// Wum96[h][96]: k<24 = (Wl1_um @ W_user); k==31 = (Wl1_um @ b_user);
// k in 32..95 = Wr1_um; else 0.
__global__ void convWum_kernel(const float* __restrict__ Wl, const float* __restrict__ Wu,
                               const float* __restrict__ bu, const float* __restrict__ Wr,
                               unsigned short* __restrict__ W96) {
  int i = blockIdx.x * 256 + threadIdx.x;
  if (i >= 64 * 96) return;
  int h = i / 96, k = i - h * 96;
  float v = 0.f;
  if (k < FU) {
    for (int j = 0; j < 64; ++j) v += Wl[h * 64 + j] * Wu[j * FU + k];
  } else if (k == 31) {
    for (int j = 0; j < 64; ++j) v += Wl[h * 64 + j] * bu[j];
  } else if (k >= 32) {
    v = Wr[h * 64 + (k - 32)];
  }
  W96[i] = f2bf(v);
}

// Movie projection via MFMA; writes bf16 hm (GEMM operand) + fp8 hm8 (gather).
__global__ __launch_bounds__(256) void proj_movie_kernel(
    const float* __restrict__ xm, const unsigned short* __restrict__ Wb,
    const float* __restrict__ bm, unsigned short* __restrict__ hm,
    unsigned char* __restrict__ hm8) {
  __shared__ unsigned short Xs[64][72];
  __shared__ unsigned short Ws[64][72];
  int t = threadIdx.x;
  int lane = t & 63, wid = t >> 6;
  int row0 = blockIdx.x * 64;
  int r0 = wid * 16;
  f32x4 acc[4];
#pragma unroll
  for (int nt = 0; nt < 4; ++nt) acc[nt] = (f32x4){0.f, 0.f, 0.f, 0.f};

  for (int k0 = 0; k0 < 448; k0 += 64) {
    int kc = min(64, FM - k0);
    __syncthreads();
    for (int i = t; i < 1024; i += 256) {
      int r = i >> 4, c4 = i & 15;
      float4 v = make_float4(0.f, 0.f, 0.f, 0.f);
      if (c4 * 4 < kc && row0 + r < NM)
        v = *(const float4*)(xm + (size_t)(row0 + r) * FM + k0 + c4 * 4);
      ushort4 o;
      o.x = f2bf(v.x); o.y = f2bf(v.y); o.z = f2bf(v.z); o.w = f2bf(v.w);
      *(ushort4*)&Xs[r][c4 * 4] = o;
    }
    for (int i = t; i < 1024; i += 256) {
      int h = i >> 4, c4 = i & 15;
      uint2 v = make_uint2(0u, 0u);
      if (c4 * 4 < kc)
        v = *(const uint2*)(Wb + (size_t)h * FM + k0 + c4 * 4);
      *(uint2*)&Ws[h][c4 * 4] = v;
    }
    __syncthreads();
#pragma unroll
    for (int kk = 0; kk < 64; kk += 32) {
      bf16x8 a = *(const bf16x8*)&Xs[r0 + (lane & 15)][kk + (lane >> 4) * 8];
#pragma unroll
      for (int nt = 0; nt < 4; ++nt) {
        bf16x8 b = *(const bf16x8*)&Ws[nt * 16 + (lane & 15)][kk + (lane >> 4) * 8];
        acc[nt] = __builtin_amdgcn_mfma_f32_16x16x32_bf16(a, b, acc[nt], 0, 0, 0);
      }
    }
  }
  int col = lane & 15;
  int rbase = r0 + (lane >> 4) * 4;
#pragma unroll
  for (int nt = 0; nt < 4; ++nt) {
    float b = bm[nt * 16 + col];
#pragma unroll
    for (int j = 0; j < 4; ++j) {
      int row = row0 + rbase + j;
      if (row < NM) {
        float v = acc[nt][j] + b;
        hm[(size_t)row * HD + nt * 16 + col] = f2bf(v);
        hm8[(size_t)row * HD + nt * 16 + col] = f2fp8(v);
      }
    }
  }
}

// ---------------- movie-side aggregation (fp8 xu table, 32B rows) ----------

__global__ __launch_bounds__(256) void agg24_kernel(
    const unsigned char* __restrict__ xu8, const int* __restrict__ rp,
    const int* __restrict__ csr, unsigned short* __restrict__ a24, int n) {
  int wid = threadIdx.x >> 6, lane = threadIdx.x & 63;
  int row = blockIdx.x * 4 + wid;
  if (row >= n) return;
  int beg = rp[row], end = rp[row + 1];
  int g = lane >> 3;       // neighbor slot 0..7
  int fq = lane & 7;       // 4 fp8 per lane
  float a0 = 0.f, a1 = 0.f, a2 = 0.f, a3 = 0.f;
  int i = beg;
  for (; i + 16 <= end; i += 16) {
    int n0 = csr[i + g];
    int n1 = csr[i + 8 + g];
    unsigned w0 = *(const unsigned*)(xu8 + (size_t)n0 * 32 + fq * 4);
    unsigned w1 = *(const unsigned*)(xu8 + (size_t)n1 * 32 + fq * 4);
    a0 += fp8dec(w0) + fp8dec(w1);
    a1 += fp8dec(w0 >> 8) + fp8dec(w1 >> 8);
    a2 += fp8dec(w0 >> 16) + fp8dec(w1 >> 16);
    a3 += fp8dec(w0 >> 24) + fp8dec(w1 >> 24);
  }
  for (; i < end; i += 8) {
    int idx = i + g;
    if (idx < end) {
      unsigned w = *(const unsigned*)(xu8 + (size_t)csr[idx] * 32 + fq * 4);
      a0 += fp8dec(w); a1 += fp8dec(w >> 8);
      a2 += fp8dec(w >> 16); a3 += fp8dec(w >> 24);
    }
  }
  a0 += __shfl_xor(a0, 8); a0 += __shfl_xor(a0, 16); a0 += __shfl_xor(a0, 32);
  a1 += __shfl_xor(a1, 8); a1 += __shfl_xor(a1, 16); a1 += __shfl_xor(a1, 32);
  a2 += __shfl_xor(a2, 8); a2 += __shfl_xor(a2, 16); a2 += __shfl_xor(a2, 32);
  a3 += __shfl_xor(a3, 8); a3 += __shfl_xor(a3, 16); a3 += __shfl_xor(a3, 32);
  if (g == 0) {
    float inv = 1.0f / fmaxf((float)(end - beg), 1.0f);
    ushort4 o;
    o.x = f2bf(a0 * inv); o.y = f2bf(a1 * inv);
    o.z = f2bf(a2 * inv); o.w = f2bf(a3 * inv);
    if (fq == 7) o.w = (end > beg) ? 0x3F80 : 0;   // col31: bf16(1.0) flag
    *(ushort4*)(a24 + (size_t)row * 32 + fq * 4) = o;
  }
}

// ---------------- user-side aggregation (fp8 hm table, 64B rows) -----------

__global__ __launch_bounds__(256) void aggU_kernel(
    const unsigned char* __restrict__ tab8, const int* __restrict__ rp,
    const int* __restrict__ csr, unsigned short* __restrict__ out, int n) {
  int wid = threadIdx.x >> 6, lane = threadIdx.x & 63;
  int row = blockIdx.x * 4 + wid;
  if (row >= n) return;
  int beg = rp[row], end = rp[row + 1];
  int g = lane >> 4;        // neighbor slot 0..3
  int fq = lane & 15;       // 4 fp8 per lane
  float a0 = 0.f, a1 = 0.f, a2 = 0.f, a3 = 0.f;
  int i = beg;
  for (; i + 16 <= end; i += 16) {
    int n0 = csr[i + g];
    int n1 = csr[i + 4 + g];
    int n2 = csr[i + 8 + g];
    int n3 = csr[i + 12 + g];
    unsigned w0 = *(const unsigned*)(tab8 + (size_t)n0 * HD + fq * 4);
    unsigned w1 = *(const unsigned*)(tab8 + (size_t)n1 * HD + fq * 4);
    unsigned w2 = *(const unsigned*)(tab8 + (size_t)n2 * HD + fq * 4);
    unsigned w3 = *(const unsigned*)(tab8 + (size_t)n3 * HD + fq * 4);
    a0 += (fp8dec(w0) + fp8dec(w1)) + (fp8dec(w2) + fp8dec(w3));
    a1 += (fp8dec(w0 >> 8) + fp8dec(w1 >> 8)) + (fp8dec(w2 >> 8) + fp8dec(w3 >> 8));
    a2 += (fp8dec(w0 >> 16) + fp8dec(w1 >> 16)) + (fp8dec(w2 >> 16) + fp8dec(w3 >> 16));
    a3 += (fp8dec(w0 >> 24) + fp8dec(w1 >> 24)) + (fp8dec(w2 >> 24) + fp8dec(w3 >> 24));
  }
  for (; i < end; i += 4) {
    int idx = i + g;
    if (idx < end) {
      unsigned w = *(const unsigned*)(tab8 + (size_t)csr[idx] * HD + fq * 4);
      a0 += fp8dec(w); a1 += fp8dec(w >> 8);
      a2 += fp8dec(w >> 16); a3 += fp8dec(w >> 24);
    }
  }
  a0 += __shfl_xor(a0, 16); a0 += __shfl_xor(a0, 32);
  a1 += __shfl_xor(a1, 16); a1 += __shfl_xor(a1, 32);
  a2 += __shfl_xor(a2, 16); a2 += __shfl_xor(a2, 32);
  a3 += __shfl_xor(a3, 16); a3 += __shfl_xor(a3, 32);
  float inv = 1.0f / fmaxf((float)(end - beg), 1.0f);
  if (lane < 16) {
    ushort4 o;
    o.x = f2bf(a0 * inv); o.y = f2bf(a1 * inv);
    o.z = f2bf(a2 * inv); o.w = f2bf(a3 * inv);
    *(ushort4*)(out + (size_t)row * HD + fq * 4) = o;
  }
}

// ---------------- SAGE linear via MFMA, K=128 (user side) ------------------

template <int OUTBF>
__global__ __launch_bounds__(256) void sage64_kernel(
    const unsigned short* __restrict__ agg, const unsigned short* __restrict__ xd,
    const unsigned short* __restrict__ Wb2, const float* __restrict__ bl,
    void* __restrict__ outp, int n) {
  __shared__ unsigned short Xs[64][136];
  __shared__ unsigned short Ws[64][136];
  int t = threadIdx.x;
  int lane = t & 63, wid = t >> 6;
  int row0 = blockIdx.x * 64;
  int r0 = wid * 16;
  for (int i = t; i < 1024; i += 256) {
    int h = i >> 4, g = i & 15;
    *(uint4*)&Ws[h][g * 8] = *(const uint4*)(Wb2 + (size_t)h * 128 + g * 8);
  }
  for (int i = t; i < 1024; i += 256) {
    int r = i >> 4, g = i & 15;
    uint4 v = make_uint4(0u, 0u, 0u, 0u);
    if (row0 + r < n) {
      if (g < 8) v = *(const uint4*)(agg + (size_t)(row0 + r) * HD + g * 8);
      else       v = *(const uint4*)(xd + (size_t)(row0 + r) * HD + (g - 8) * 8);
    }
    *(uint4*)&Xs[r][g * 8] = v;
  }
  __syncthreads();
  f32x4 acc[4];
#pragma unroll
  for (int nt = 0; nt < 4; ++nt) acc[nt] = (f32x4){0.f, 0.f, 0.f, 0.f};
#pragma unroll
  for (int kk = 0; kk < 128; kk += 32) {
    bf16x8 a = *(const bf16x8*)&Xs[r0 + (lane & 15)][kk + (lane >> 4) * 8];
#pragma unroll
    for (int nt = 0; nt < 4; ++nt) {
      bf16x8 b = *(const bf16x8*)&Ws[nt * 16 + (lane & 15)][kk + (lane >> 4) * 8];
      acc[nt] = __builtin_amdgcn_mfma_f32_16x16x32_bf16(a, b, acc[nt], 0, 0, 0);
    }
  }
  int col = lane & 15;
  int rbase = r0 + (lane >> 4) * 4;
#pragma unroll
  for (int nt = 0; nt < 4; ++nt) {
    float b = bl[nt * 16 + col];
#pragma unroll
    for (int j = 0; j < 4; ++j) {
      int row = row0 + rbase + j;
      if (row < n) {
        float v = fmaxf(acc[nt][j] + b, 0.f);
        if (OUTBF) ((unsigned short*)outp)[(size_t)row * HD + nt * 16 + col] = f2bf(v);
        else       ((float*)outp)[(size_t)row * HD + nt * 16 + col] = v;
      }
    }
  }
}

// ---------------- SAGE linear via MFMA, K=96 (movie side, folded proj) -----

__global__ __launch_bounds__(256) void sage_um_kernel(
    const unsigned short* __restrict__ a24, const unsigned short* __restrict__ hm,
    const unsigned short* __restrict__ W96, const float* __restrict__ bl,
    unsigned short* __restrict__ m1, int n) {
  __shared__ unsigned short Xs[64][104];
  __shared__ unsigned short Ws[64][104];
  int t = threadIdx.x;
  int lane = t & 63, wid = t >> 6;
  int row0 = blockIdx.x * 64;
  int r0 = wid * 16;
  for (int i = t; i < 768; i += 256) {
    int h = i / 12, g = i - h * 12;
    *(uint4*)&Ws[h][g * 8] = *(const uint4*)(W96 + (size_t)h * 96 + g * 8);
  }
  for (int i = t; i < 768; i += 256) {
    int r = i / 12, g = i - r * 12;
    uint4 v = make_uint4(0u, 0u, 0u, 0u);
    if (row0 + r < n) {
      if (g < 4) v = *(const uint4*)(a24 + (size_t)(row0 + r) * 32 + g * 8);
      else       v = *(const uint4*)(hm + (size_t)(row0 + r) * HD + (g - 4) * 8);
    }
    *(uint4*)&Xs[r][g * 8] = v;
  }
  __syncthreads();
  f32x4 acc[4];
#pragma unroll
  for (int nt = 0; nt < 4; ++nt) acc[nt] = (f32x4){0.f, 0.f, 0.f, 0.f};
#pragma unroll
  for (int kk = 0; kk < 96; kk += 32) {
    bf16x8 a = *(const bf16x8*)&Xs[r0 + (lane & 15)][kk + (lane >> 4) * 8];
#pragma unroll
    for (int nt = 0; nt < 4; ++nt) {
      bf16x8 b = *(const bf16x8*)&Ws[nt * 16 + (lane & 15)][kk + (lane >> 4) * 8];
      acc[nt] = __builtin_amdgcn_mfma_f32_16x16x32_bf16(a, b, acc[nt], 0, 0, 0);
    }
  }
  int col = lane & 15;
  int rbase = r0 + (lane >> 4) * 4;
#pragma unroll
  for (int nt = 0; nt < 4; ++nt) {
    float b = bl[nt * 16 + col];
#pragma unroll
    for (int j = 0; j < 4; ++j) {
      int row = row0 + rbase + j;
      if (row < n)
        m1[(size_t)row * HD + nt * 16 + col] = f2bf(fmaxf(acc[nt][j] + b, 0.f));
    }
  }
}

// ---------------- layer 2 (z-trick) ----------------

__global__ __launch_bounds__(256) void zproj_kernel(
    const unsigned short* __restrict__ u1, const float* __restrict__ Wl2,
    float4* __restrict__ z) {
  __shared__ float W[3][64];
  int t = threadIdx.x;
  if (t < 192) W[t / 64][t & 63] = Wl2[t];
  __syncthreads();
  int wid = t >> 6, lane = t & 63;
  int g = lane >> 4, fq = lane & 15;
  int row = blockIdx.x * 16 + wid * 4 + g;
  if (row >= NU) return;
  uint2 v = *(const uint2*)(u1 + (size_t)row * HD + fq * 4);
  float2 p0 = unpk(v.x), p1 = unpk(v.y);
  int f = fq * 4;
  float z0 = p0.x * W[0][f] + p0.y * W[0][f + 1] + p1.x * W[0][f + 2] + p1.y * W[0][f + 3];
  float z1 = p0.x * W[1][f] + p0.y * W[1][f + 1] + p1.x * W[1][f + 2] + p1.y * W[1][f + 3];
  float z2 = p0.x * W[2][f] + p0.y * W[2][f + 1] + p1.x * W[2][f + 2] + p1.y * W[2][f + 3];
#pragma unroll
  for (int off = 1; off < 16; off <<= 1) {
    z0 += __shfl_xor(z0, off);
    z1 += __shfl_xor(z1, off);
    z2 += __shfl_xor(z2, off);
  }
  if (fq == 0) z[row] = make_float4(z0, z1, z2, 0.f);
}

__global__ __launch_bounds__(256) void agg4_kernel(
    const float4* __restrict__ z, const int* __restrict__ rp,
    const int* __restrict__ csr, float4* __restrict__ zagg, int n) {
  int wid = threadIdx.x >> 6, lane = threadIdx.x & 63;
  int row = blockIdx.x * 4 + wid;
  if (row >= n) return;
  int beg = rp[row], end = rp[row + 1];
  float s0 = 0.f, s1 = 0.f, s2 = 0.f;
  for (int i = beg + lane; i < end; i += 64) {
    float4 v = z[csr[i]];
    s0 += v.x; s1 += v.y; s2 += v.z;
  }
#pragma unroll
  for (int off = 1; off < 64; off <<= 1) {
    s0 += __shfl_xor(s0, off);
    s1 += __shfl_xor(s1, off);
    s2 += __shfl_xor(s2, off);
  }
  if (lane == 0) {
    float inv = 1.0f / fmaxf((float)(end - beg), 1.0f);
    zagg[row] = make_float4(s0 * inv, s1 * inv, s2 * inv, 0.f);
  }
}

__global__ void out2_kernel(const float4* __restrict__ zagg,
                            const unsigned short* __restrict__ m1,
                            const float* __restrict__ Wr2, const float* __restrict__ bl2,
                            float* __restrict__ out, int n) {
  int wid = threadIdx.x >> 6, lane = threadIdx.x & 63;
  int row = blockIdx.x * 4 + wid;
  if (row >= n) return;
  float mm = bf2f(m1[(size_t)row * HD + lane]);
  float4 za = zagg[row];
  float zc[3] = {za.x, za.y, za.z};
#pragma unroll
  for (int g = 0; g < 3; ++g) {
    float p = mm * Wr2[g * HD + lane];
#pragma unroll
    for (int off = 32; off > 0; off >>= 1) p += __shfl_down(p, off);
    if (lane == 0) out[row * 3 + g] = p + zc[g] + bl2[g];
  }
}

// ---------------------------------------------------------------------------

extern "C" void kernel_launch(void* const* d_in, const int* in_sizes, int n_in,
                              void* d_out, int out_size, void* d_ws, size_t ws_size,
                              hipStream_t stream) {
  const float* x_user  = (const float*)d_in[0];
  const float* x_movie = (const float*)d_in[1];
  const int*   e_src   = (const int*)d_in[2];
  const int*   e_dst   = (const int*)d_in[3];
  const float* W_user  = (const float*)d_in[4];
  const float* b_user  = (const float*)d_in[5];
  const float* W_movie = (const float*)d_in[6];
  const float* b_movie = (const float*)d_in[7];
  const float* Wl1_um  = (const float*)d_in[8];
  const float* bl1_um  = (const float*)d_in[9];
  const float* Wr1_um  = (const float*)d_in[10];
  const float* Wl1_mu  = (const float*)d_in[11];
  const float* bl1_mu  = (const float*)d_in[12];
  const float* Wr1_mu  = (const float*)d_in[13];
  const float* Wl2_um  = (const float*)d_in[14];
  const float* bl2_um  = (const float*)d_in[15];
  const float* Wr2_um  = (const float*)d_in[16];
  float* outp = (float*)d_out;

  // ---- workspace carve-up ----
  char* p = (char*)d_ws;
  size_t off = 0;
  auto take = [&](size_t bytes) { void* r = p + off; off += alignup(bytes); return r; };

  int* rp_m    = (int*)take(size_t(NM + 1) * 4);
  int* rp_u    = (int*)take(size_t(NU + 1) * 4);
  int* bh      = (int*)take(size_t(NBK) * 4);
  int* bbase_m = (int*)take(size_t(MBK + 1) * 4);
  int* bbase_u = (int*)take(size_t(UBK + 1) * 4);
  int* bcur_m  = (int*)take(size_t(MBK) * 4);
  int* bcur_u  = (int*)take(size_t(UBK) * 4);
  int* csr_m   = (int*)take(size_t(NE) * 4);
  int* csr_u   = (int*)take(size_t(NE) * 4);

  // overlay: staging (build phase) aliases feature buffers (feature phase)
  size_t ov_base = off;
  unsigned* stage_m = (unsigned*)take(size_t(NE) * 4);
  unsigned* stage_u = (unsigned*)take(size_t(NE) * 4);
  size_t stage_end = off;
  off = ov_base;
  unsigned short* hu   = (unsigned short*)take(size_t(NU) * HD * 2);
  unsigned short* hm   = (unsigned short*)take(size_t(NM) * HD * 2);
  unsigned short* u1   = (unsigned short*)take(size_t(NU) * HD * 2);
  unsigned short* m1   = (unsigned short*)take(size_t(NM) * HD * 2);
  unsigned short* aggb = (unsigned short*)take(size_t(NU) * HD * 2);
  unsigned char*  xu8  = (unsigned char*)take(size_t(NU) * 32);
  unsigned char*  hm8  = (unsigned char*)take(size_t(NM) * HD);
  unsigned short* a24  = (unsigned short*)take(size_t(NM) * 32 * 2);
  if (off < stage_end) off = stage_end;
  float4* z    = (float4*)take(size_t(NU) * 16);
  float4* zagg = (float4*)take(size_t(NM) * 16);
  unsigned short* Wb    = (unsigned short*)take(size_t(HD) * FM * 2);
  unsigned short* Wmu   = (unsigned short*)take(size_t(HD) * 128 * 2);
  unsigned short* Wum96 = (unsigned short*)take(size_t(HD) * 96 * 2);
  if (off > ws_size) return;

  const int TB = 256;

  // ---- CSR build ----
  hipMemsetAsync(bh, 0, size_t(NBK) * 4, stream);
  histB_kernel<<<512, 256, 0, stream>>>(e_src, e_dst, bh);
  scanB_kernel<<<1, 1024, 0, stream>>>(bh, bbase_m, bbase_u, bcur_m, bcur_u);
  passA_kernel<<<(NE + EPB - 1) / EPB, 1024, 0, stream>>>(e_src, e_dst, bcur_m, bcur_u,
                                                          stage_m, stage_u);
  passB_kernel<<<NBK, 1024, 0, stream>>>(bbase_m, bbase_u, stage_m, stage_u,
                                         csr_m, csr_u, rp_m, rp_u);

  // ---- projections + conversions ----
  convW_kernel<<<(HD * FM + 255) / 256, 256, 0, stream>>>(W_movie, Wb, HD * FM);
  convW2_kernel<<<(HD * 128 + 255) / 256, 256, 0, stream>>>(Wl1_mu, Wr1_mu, Wmu);
  convWum_kernel<<<(64 * 96 + 255) / 256, 256, 0, stream>>>(Wl1_um, W_user, b_user,
                                                            Wr1_um, Wum96);
  convXu_kernel<<<(NU * 32 + 255) / 256, 256, 0, stream>>>(x_user, xu8);
  proj_user_kernel<<<NU / 16, TB, 0, stream>>>(x_user, W_user, b_user, hu);
  proj_movie_kernel<<<(NM + 63) / 64, TB, 0, stream>>>(x_movie, Wb, b_movie, hm, hm8);

  // ---- layer 1: movie side ----
  agg24_kernel<<<(NM + 3) / 4, TB, 0, stream>>>(xu8, rp_m, csr_m, a24, NM);
  sage_um_kernel<<<(NM + 63) / 64, TB, 0, stream>>>(a24, hm, Wum96, bl1_um, m1, NM);

  // ---- layer 1: user side ----
  aggU_kernel<<<(NU + 3) / 4, TB, 0, stream>>>(hm8, rp_u, csr_u, aggb, NU);
  sage64_kernel<1><<<(NU + 63) / 64, TB, 0, stream>>>(aggb, hu, Wmu, bl1_mu, u1, NU);

  // ---- layer 2 (z-trick) ----
  zproj_kernel<<<(NU + 15) / 16, TB, 0, stream>>>(u1, Wl2_um, z);
  agg4_kernel<<<(NM + 3) / 4, TB, 0, stream>>>(z, rp_m, csr_m, zagg, NM);
  out2_kernel<<<(NM + 3) / 4, TB, 0, stream>>>(zagg, m1, Wr2_um, bl2_um, outp, NM);
}

// Round 15
// 341.681 us; speedup vs baseline: 1.3366x; 1.0646x over previous
//
#include <hip/hip_runtime.h>

// ---------------------------------------------------------------------------
// Hetero GraphSAGE (user<->movie). LDS-binned bucketed CSR build, fp8 gather
// tables decoded with HW v_cvt_pk_f32_fp8, MFMA GEMMs, folded projections,
// layer-2 z-trick.
// ---------------------------------------------------------------------------

constexpr int NU = 100000;   // users
constexpr int NM = 50000;    // movies
constexpr int NE = 4000000;  // edges
constexpr int FU = 24;       // user feat
constexpr int FM = 404;      // movie feat
constexpr int HD = 64;       // hidden

constexpr int BSH = 8;                       // bucket = 256 node ids
constexpr int MBK = (NM + 255) >> BSH;       // 196 movie buckets
constexpr int UBK = (NU + 255) >> BSH;       // 391 user buckets
constexpr int NBK = MBK + UBK;               // 587
constexpr int EPB = 8192;                    // edges per passA block (1024 thr x 8)

static inline size_t alignup(size_t x) { return (x + 255) & ~size_t(255); }

__device__ __forceinline__ float bf2f(unsigned short h) {
  return __uint_as_float(((unsigned int)h) << 16);
}
__device__ __forceinline__ unsigned short f2bf(float f) {
  unsigned int u = __float_as_uint(f);
  u = (u + 0x7FFFu + ((u >> 16) & 1u)) >> 16;   // RNE
  return (unsigned short)u;
}
__device__ __forceinline__ float2 unpk(unsigned u) {
  return make_float2(__uint_as_float(u << 16), __uint_as_float(u & 0xFFFF0000u));
}
// fp8 e4m3fn software decode (low 8 bits of v)
__device__ __forceinline__ float fp8dec(unsigned v) {
  unsigned u = ((v & 0x80u) << 24) | ((v & 0x7Fu) << 20);
  return __uint_as_float(u) * 0x1p120f;
}
// fp8 e4m3fn encode, RNE, clamp to +-448
__device__ __forceinline__ unsigned char f2fp8(float f) {
  float a = fminf(fabsf(f), 448.0f);
  unsigned u = __float_as_uint(a * 0x1p-120f);
  u = u + 0x7FFFFu + ((u >> 20) & 1u);
  return (unsigned char)(((u >> 20) & 0x7Fu) | ((__float_as_uint(f) >> 24) & 0x80u));
}

typedef __attribute__((ext_vector_type(2))) float f2v;

#if __has_builtin(__builtin_amdgcn_cvt_pk_f32_fp8)
#define FP8_HW 1
#endif

// decode bytes 0,1 of w -> float2
__device__ __forceinline__ f2v fp8lo(unsigned w) {
#ifdef FP8_HW
  return __builtin_amdgcn_cvt_pk_f32_fp8(w, false);
#else
  f2v r; r.x = fp8dec(w); r.y = fp8dec(w >> 8); return r;
#endif
}
// decode bytes 2,3 of w -> float2
__device__ __forceinline__ f2v fp8hi(unsigned w) {
#ifdef FP8_HW
  return __builtin_amdgcn_cvt_pk_f32_fp8(w, true);
#else
  f2v r; r.x = fp8dec(w >> 16); r.y = fp8dec(w >> 24); return r;
#endif
}

using bf16x8 = __attribute__((ext_vector_type(8))) short;   // 8 bf16 = 4 VGPRs
using f32x4  = __attribute__((ext_vector_type(4))) float;   // MFMA C/D frag

// ---------------- CSR build ----------------

__global__ __launch_bounds__(256) void histB_kernel(const int* __restrict__ src,
                                                    const int* __restrict__ dst,
                                                    int* __restrict__ bh) {
  __shared__ int h[NBK];
  for (int i = threadIdx.x; i < NBK; i += 256) h[i] = 0;
  __syncthreads();
  int idx = blockIdx.x * 256 + threadIdx.x;
  int stride = gridDim.x * 256;
  for (int i = idx; i < NE; i += stride) {
    atomicAdd(&h[dst[i] >> BSH], 1);
    atomicAdd(&h[MBK + (src[i] >> BSH)], 1);
  }
  __syncthreads();
  for (int i = threadIdx.x; i < NBK; i += 256) {
    int c = h[i];
    if (c) atomicAdd(&bh[i], c);
  }
}

__global__ __launch_bounds__(1024) void scanB_kernel(const int* __restrict__ bh,
                                                     int* __restrict__ bbase_m,
                                                     int* __restrict__ bbase_u,
                                                     int* __restrict__ bcur_m,
                                                     int* __restrict__ bcur_u) {
  __shared__ int tmp[1024];
  int t = threadIdx.x;
  int vm = (t < MBK) ? bh[t] : 0;
  tmp[t] = vm;
  __syncthreads();
  for (int off = 1; off < 1024; off <<= 1) {
    int v = (t >= off) ? tmp[t - off] : 0;
    __syncthreads();
    tmp[t] += v;
    __syncthreads();
  }
  if (t < MBK) {
    int e = tmp[t] - vm;
    bbase_m[t] = e; bcur_m[t] = e;
    if (t == MBK - 1) bbase_m[MBK] = tmp[t];
  }
  __syncthreads();
  int vu = (t < UBK) ? bh[MBK + t] : 0;
  tmp[t] = vu;
  __syncthreads();
  for (int off = 1; off < 1024; off <<= 1) {
    int v = (t >= off) ? tmp[t - off] : 0;
    __syncthreads();
    tmp[t] += v;
    __syncthreads();
  }
  if (t < UBK) {
    int e = tmp[t] - vu;
    bbase_u[t] = e; bcur_u[t] = e;
    if (t == UBK - 1) bbase_u[UBK] = tmp[t];
  }
}

// Pass A with LDS binning (round-14 config, verified).
__global__ __launch_bounds__(1024) void passA_kernel(
    const int* __restrict__ src, const int* __restrict__ dst,
    int* __restrict__ bcur_m, int* __restrict__ bcur_u,
    unsigned* __restrict__ stage_m, unsigned* __restrict__ stage_u) {
  __shared__ int hB[NBK];
  __shared__ int cntB[NBK];
  __shared__ int gB[NBK];
  __shared__ int tmp[1024];
  __shared__ unsigned binM[EPB];
  __shared__ unsigned binU[EPB];
  int t = threadIdx.x;
  for (int i = t; i < NBK; i += 1024) hB[i] = 0;
  __syncthreads();
  int e0 = blockIdx.x * EPB + t;
  int sv[8], dv[8], rm[8], ru[8];
#pragma unroll
  for (int k = 0; k < 8; ++k) {
    int e = e0 + k * 1024;
    if (e < NE) {
      int s = src[e], d = dst[e];
      sv[k] = s; dv[k] = d;
      rm[k] = atomicAdd(&hB[d >> BSH], 1);
      ru[k] = atomicAdd(&hB[MBK + (s >> BSH)], 1);
    } else {
      sv[k] = -1;
    }
  }
  __syncthreads();
  int cm = (t < MBK) ? hB[t] : 0;
  tmp[t] = cm;
  __syncthreads();
  for (int off = 1; off < 1024; off <<= 1) {
    int v = (t >= off) ? tmp[t - off] : 0;
    __syncthreads();
    tmp[t] += v;
    __syncthreads();
  }
  int lofsM = tmp[t] - cm;
  __syncthreads();
  int cu_ = (t < UBK) ? hB[MBK + t] : 0;
  tmp[t] = cu_;
  __syncthreads();
  for (int off = 1; off < 1024; off <<= 1) {
    int v = (t >= off) ? tmp[t - off] : 0;
    __syncthreads();
    tmp[t] += v;
    __syncthreads();
  }
  int lofsU = tmp[t] - cu_;
  __syncthreads();
  if (t < MBK) { cntB[t] = cm; hB[t] = lofsM; }
  if (t < UBK) { cntB[MBK + t] = cu_; hB[MBK + t] = lofsU; }
  __syncthreads();
#pragma unroll
  for (int k = 0; k < 8; ++k) {
    if (sv[k] >= 0) {
      int s = sv[k], d = dv[k];
      binM[hB[d >> BSH] + rm[k]] = ((unsigned)(d & 255) << 24) | (unsigned)s;
      binU[hB[MBK + (s >> BSH)] + ru[k]] = ((unsigned)(s & 255) << 24) | (unsigned)d;
    }
  }
  __syncthreads();
  for (int b = t; b < NBK; b += 1024) {
    int cc = cntB[b];
    if (cc) {
      int gb = (b < MBK) ? atomicAdd(&bcur_m[b], cc) : atomicAdd(&bcur_u[b - MBK], cc);
      gB[b] = gb - hB[b];
    }
  }
  __syncthreads();
  int wv = t >> 6, ln = t & 63;
  for (int b = wv; b < MBK; b += 16) {
    int cc = cntB[b], lo = hB[b], go = hB[b] + gB[b];
    for (int j = ln; j < cc; j += 64) stage_m[go + j] = binM[lo + j];
  }
  for (int b = wv; b < UBK; b += 16) {
    int cc = cntB[MBK + b], lo = hB[MBK + b], go = hB[MBK + b] + gB[MBK + b];
    for (int j = ln; j < cc; j += 64) stage_u[go + j] = binU[lo + j];
  }
}

__global__ __launch_bounds__(1024) void passB_kernel(
    const int* __restrict__ bbase_m, const int* __restrict__ bbase_u,
    const unsigned* __restrict__ stage_m, const unsigned* __restrict__ stage_u,
    int* __restrict__ csr_m, int* __restrict__ csr_u,
    int* __restrict__ rp_m, int* __restrict__ rp_u) {
  __shared__ int cnt[256];
  __shared__ int sc[256];
  int b = blockIdx.x;
  const unsigned* stage; int* csr; int* rp; int idbase, ntot, bb, be;
  if (b < MBK) {
    stage = stage_m; csr = csr_m; rp = rp_m;
    idbase = b << BSH; ntot = NM;
    bb = bbase_m[b]; be = bbase_m[b + 1];
  } else {
    int c = b - MBK;
    stage = stage_u; csr = csr_u; rp = rp_u;
    idbase = c << BSH; ntot = NU;
    bb = bbase_u[c]; be = bbase_u[c + 1];
  }
  int nloc = min(256, ntot - idbase);
  int t = threadIdx.x;
  if (t < 256) cnt[t] = 0;
  __syncthreads();
  for (int j = bb + t; j < be; j += 1024) atomicAdd(&cnt[stage[j] >> 24], 1);
  __syncthreads();
  int c0 = (t < 256) ? cnt[t] : 0;
  if (t < 256) sc[t] = c0;
  __syncthreads();
  for (int off = 1; off < 256; off <<= 1) {
    int v = 0;
    if (t < 256 && t >= off) v = sc[t - off];
    __syncthreads();
    if (t < 256) sc[t] += v;
    __syncthreads();
  }
  if (t < nloc) {
    int e = bb + sc[t] - c0;
    rp[idbase + t] = e;
    cnt[t] = e;                     // reuse as cursor
  }
  if (t == 0 && idbase + nloc == ntot) rp[ntot] = be;
  __syncthreads();
  for (int j = bb + t; j < be; j += 1024) {
    unsigned e = stage[j];
    int pos = atomicAdd(&cnt[e >> 24], 1);
    csr[pos] = (int)(e & 0xFFFFFFu);
  }
}

// ---------------- input projections / conversions ----------------

__global__ void proj_user_kernel(const float* __restrict__ xu, const float* __restrict__ Wu,
                                 const float* __restrict__ bu, unsigned short* __restrict__ hu) {
  __shared__ float Wt[FU][HD + 1];
  __shared__ float Xl[16][FU];
  int t = threadIdx.x;
  int lane = t & 63, wg = t >> 6;
  int row0 = blockIdx.x * 16;
  for (int h = wg; h < HD; h += 4)
    if (lane < FU) Wt[lane][h] = Wu[h * FU + lane];
  for (int r = wg; r < 16; r += 4)
    if (lane < FU) Xl[r][lane] = xu[(row0 + r) * FU + lane];
  __syncthreads();
  float b = bu[lane];
  float acc[4] = {0.f, 0.f, 0.f, 0.f};
  for (int k = 0; k < FU; ++k) {
    float w = Wt[k][lane];
#pragma unroll
    for (int j = 0; j < 4; ++j) acc[j] += Xl[wg * 4 + j][k] * w;
  }
#pragma unroll
  for (int j = 0; j < 4; ++j)
    hu[(row0 + wg * 4 + j) * HD + lane] = f2bf(acc[j] + b);
}

// x_user fp32 [NU][24] -> fp8 [NU][32] (cols 24..31 zero)
__global__ void convXu_kernel(const float* __restrict__ xu, unsigned char* __restrict__ xu8) {
  int i = blockIdx.x * 256 + threadIdx.x;
  if (i < NU * 32) {
    int r = i >> 5, c = i & 31;
    xu8[i] = (c < FU) ? f2fp8(xu[r * FU + c]) : 0;
  }
}

__global__ void convW_kernel(const float* __restrict__ W, unsigned short* __restrict__ Wb,
                             int n) {
  int i = blockIdx.x * 256 + threadIdx.x;
  if (i < n) Wb[i] = f2bf(W[i]);
}

__global__ void convW2_kernel(const float* __restrict__ Wl, const float* __restrict__ Wr,
                              unsigned short* __restrict__ Wb2) {
  int i = blockIdx.x * 256 + threadIdx.x;
  if (i < HD * 128) {
    int h = i >> 7, k = i & 127;
    float v = (k < 64) ? Wl[h * 64 + k] : Wr[h * 64 + (k - 64)];
    Wb2[i] = f2bf(v);
  }
}

// Wum96[h][96]: k<24 = (Wl1_um @ W_user); k==31 = (Wl1_um @ b_user);
// k in 32..95 = Wr1_um; else 0.
__global__ void convWum_kernel(const float* __restrict__ Wl, const float* __restrict__ Wu,
                               const float* __restrict__ bu, const float* __restrict__ Wr,
                               unsigned short* __restrict__ W96) {
  int i = blockIdx.x * 256 + threadIdx.x;
  if (i >= 64 * 96) return;
  int h = i / 96, k = i - h * 96;
  float v = 0.f;
  if (k < FU) {
    for (int j = 0; j < 64; ++j) v += Wl[h * 64 + j] * Wu[j * FU + k];
  } else if (k == 31) {
    for (int j = 0; j < 64; ++j) v += Wl[h * 64 + j] * bu[j];
  } else if (k >= 32) {
    v = Wr[h * 64 + (k - 32)];
  }
  W96[i] = f2bf(v);
}

// Movie projection via MFMA; writes bf16 hm + fp8 hm8.
__global__ __launch_bounds__(256) void proj_movie_kernel(
    const float* __restrict__ xm, const unsigned short* __restrict__ Wb,
    const float* __restrict__ bm, unsigned short* __restrict__ hm,
    unsigned char* __restrict__ hm8) {
  __shared__ unsigned short Xs[64][72];
  __shared__ unsigned short Ws[64][72];
  int t = threadIdx.x;
  int lane = t & 63, wid = t >> 6;
  int row0 = blockIdx.x * 64;
  int r0 = wid * 16;
  f32x4 acc[4];
#pragma unroll
  for (int nt = 0; nt < 4; ++nt) acc[nt] = (f32x4){0.f, 0.f, 0.f, 0.f};

  for (int k0 = 0; k0 < 448; k0 += 64) {
    int kc = min(64, FM - k0);
    __syncthreads();
    for (int i = t; i < 1024; i += 256) {
      int r = i >> 4, c4 = i & 15;
      float4 v = make_float4(0.f, 0.f, 0.f, 0.f);
      if (c4 * 4 < kc && row0 + r < NM)
        v = *(const float4*)(xm + (size_t)(row0 + r) * FM + k0 + c4 * 4);
      ushort4 o;
      o.x = f2bf(v.x); o.y = f2bf(v.y); o.z = f2bf(v.z); o.w = f2bf(v.w);
      *(ushort4*)&Xs[r][c4 * 4] = o;
    }
    for (int i = t; i < 1024; i += 256) {
      int h = i >> 4, c4 = i & 15;
      uint2 v = make_uint2(0u, 0u);
      if (c4 * 4 < kc)
        v = *(const uint2*)(Wb + (size_t)h * FM + k0 + c4 * 4);
      *(uint2*)&Ws[h][c4 * 4] = v;
    }
    __syncthreads();
#pragma unroll
    for (int kk = 0; kk < 64; kk += 32) {
      bf16x8 a = *(const bf16x8*)&Xs[r0 + (lane & 15)][kk + (lane >> 4) * 8];
#pragma unroll
      for (int nt = 0; nt < 4; ++nt) {
        bf16x8 b = *(const bf16x8*)&Ws[nt * 16 + (lane & 15)][kk + (lane >> 4) * 8];
        acc[nt] = __builtin_amdgcn_mfma_f32_16x16x32_bf16(a, b, acc[nt], 0, 0, 0);
      }
    }
  }
  int col = lane & 15;
  int rbase = r0 + (lane >> 4) * 4;
#pragma unroll
  for (int nt = 0; nt < 4; ++nt) {
    float b = bm[nt * 16 + col];
#pragma unroll
    for (int j = 0; j < 4; ++j) {
      int row = row0 + rbase + j;
      if (row < NM) {
        float v = acc[nt][j] + b;
        hm[(size_t)row * HD + nt * 16 + col] = f2bf(v);
        hm8[(size_t)row * HD + nt * 16 + col] = f2fp8(v);
      }
    }
  }
}

// ---------------- movie-side aggregation (fp8 xu table, HW cvt) ------------

__global__ __launch_bounds__(256) void agg24_kernel(
    const unsigned char* __restrict__ xu8, const int* __restrict__ rp,
    const int* __restrict__ csr, unsigned short* __restrict__ a24, int n) {
  int wid = threadIdx.x >> 6, lane = threadIdx.x & 63;
  int row = blockIdx.x * 4 + wid;
  if (row >= n) return;
  int beg = rp[row], end = rp[row + 1];
  int g = lane >> 3;       // neighbor slot 0..7
  int fq = lane & 7;       // 4 fp8 per lane
  f2v a01 = {0.f, 0.f}, a23 = {0.f, 0.f};
  int i = beg;
  for (; i + 16 <= end; i += 16) {
    int n0 = csr[i + g];
    int n1 = csr[i + 8 + g];
    unsigned w0 = *(const unsigned*)(xu8 + (size_t)n0 * 32 + fq * 4);
    unsigned w1 = *(const unsigned*)(xu8 + (size_t)n1 * 32 + fq * 4);
    a01 += fp8lo(w0) + fp8lo(w1);
    a23 += fp8hi(w0) + fp8hi(w1);
  }
  for (; i < end; i += 8) {
    int idx = i + g;
    if (idx < end) {
      unsigned w = *(const unsigned*)(xu8 + (size_t)csr[idx] * 32 + fq * 4);
      a01 += fp8lo(w);
      a23 += fp8hi(w);
    }
  }
  float a0 = a01.x, a1 = a01.y, a2 = a23.x, a3 = a23.y;
  a0 += __shfl_xor(a0, 8); a0 += __shfl_xor(a0, 16); a0 += __shfl_xor(a0, 32);
  a1 += __shfl_xor(a1, 8); a1 += __shfl_xor(a1, 16); a1 += __shfl_xor(a1, 32);
  a2 += __shfl_xor(a2, 8); a2 += __shfl_xor(a2, 16); a2 += __shfl_xor(a2, 32);
  a3 += __shfl_xor(a3, 8); a3 += __shfl_xor(a3, 16); a3 += __shfl_xor(a3, 32);
  if (g == 0) {
    float inv = 1.0f / fmaxf((float)(end - beg), 1.0f);
    ushort4 o;
    o.x = f2bf(a0 * inv); o.y = f2bf(a1 * inv);
    o.z = f2bf(a2 * inv); o.w = f2bf(a3 * inv);
    if (fq == 7) o.w = (end > beg) ? 0x3F80 : 0;   // col31: bf16(1.0) flag
    *(ushort4*)(a24 + (size_t)row * 32 + fq * 4) = o;
  }
}

// ---------------- user-side aggregation (fp8 hm table, HW cvt) -------------

__global__ __launch_bounds__(256) void aggU_kernel(
    const unsigned char* __restrict__ tab8, const int* __restrict__ rp,
    const int* __restrict__ csr, unsigned short* __restrict__ out, int n) {
  int wid = threadIdx.x >> 6, lane = threadIdx.x & 63;
  int row = blockIdx.x * 4 + wid;
  if (row >= n) return;
  int beg = rp[row], end = rp[row + 1];
  int g = lane >> 4;        // neighbor slot 0..3
  int fq = lane & 15;       // 4 fp8 per lane
  f2v a01 = {0.f, 0.f}, a23 = {0.f, 0.f};
  int i = beg;
  for (; i + 16 <= end; i += 16) {
    int n0 = csr[i + g];
    int n1 = csr[i + 4 + g];
    int n2 = csr[i + 8 + g];
    int n3 = csr[i + 12 + g];
    unsigned w0 = *(const unsigned*)(tab8 + (size_t)n0 * HD + fq * 4);
    unsigned w1 = *(const unsigned*)(tab8 + (size_t)n1 * HD + fq * 4);
    unsigned w2 = *(const unsigned*)(tab8 + (size_t)n2 * HD + fq * 4);
    unsigned w3 = *(const unsigned*)(tab8 + (size_t)n3 * HD + fq * 4);
    a01 += (fp8lo(w0) + fp8lo(w1)) + (fp8lo(w2) + fp8lo(w3));
    a23 += (fp8hi(w0) + fp8hi(w1)) + (fp8hi(w2) + fp8hi(w3));
  }
  for (; i < end; i += 4) {
    int idx = i + g;
    if (idx < end) {
      unsigned w = *(const unsigned*)(tab8 + (size_t)csr[idx] * HD + fq * 4);
      a01 += fp8lo(w);
      a23 += fp8hi(w);
    }
  }
  float a0 = a01.x, a1 = a01.y, a2 = a23.x, a3 = a23.y;
  a0 += __shfl_xor(a0, 16); a0 += __shfl_xor(a0, 32);
  a1 += __shfl_xor(a1, 16); a1 += __shfl_xor(a1, 32);
  a2 += __shfl_xor(a2, 16); a2 += __shfl_xor(a2, 32);
  a3 += __shfl_xor(a3, 16); a3 += __shfl_xor(a3, 32);
  float inv = 1.0f / fmaxf((float)(end - beg), 1.0f);
  if (lane < 16) {
    ushort4 o;
    o.x = f2bf(a0 * inv); o.y = f2bf(a1 * inv);
    o.z = f2bf(a2 * inv); o.w = f2bf(a3 * inv);
    *(ushort4*)(out + (size_t)row * HD + fq * 4) = o;
  }
}

// ---------------- SAGE linear via MFMA, K=128 (user side) ------------------

template <int OUTBF>
__global__ __launch_bounds__(256) void sage64_kernel(
    const unsigned short* __restrict__ agg, const unsigned short* __restrict__ xd,
    const unsigned short* __restrict__ Wb2, const float* __restrict__ bl,
    void* __restrict__ outp, int n) {
  __shared__ unsigned short Xs[64][136];
  __shared__ unsigned short Ws[64][136];
  int t = threadIdx.x;
  int lane = t & 63, wid = t >> 6;
  int row0 = blockIdx.x * 64;
  int r0 = wid * 16;
  for (int i = t; i < 1024; i += 256) {
    int h = i >> 4, g = i & 15;
    *(uint4*)&Ws[h][g * 8] = *(const uint4*)(Wb2 + (size_t)h * 128 + g * 8);
  }
  for (int i = t; i < 1024; i += 256) {
    int r = i >> 4, g = i & 15;
    uint4 v = make_uint4(0u, 0u, 0u, 0u);
    if (row0 + r < n) {
      if (g < 8) v = *(const uint4*)(agg + (size_t)(row0 + r) * HD + g * 8);
      else       v = *(const uint4*)(xd + (size_t)(row0 + r) * HD + (g - 8) * 8);
    }
    *(uint4*)&Xs[r][g * 8] = v;
  }
  __syncthreads();
  f32x4 acc[4];
#pragma unroll
  for (int nt = 0; nt < 4; ++nt) acc[nt] = (f32x4){0.f, 0.f, 0.f, 0.f};
#pragma unroll
  for (int kk = 0; kk < 128; kk += 32) {
    bf16x8 a = *(const bf16x8*)&Xs[r0 + (lane & 15)][kk + (lane >> 4) * 8];
#pragma unroll
    for (int nt = 0; nt < 4; ++nt) {
      bf16x8 b = *(const bf16x8*)&Ws[nt * 16 + (lane & 15)][kk + (lane >> 4) * 8];
      acc[nt] = __builtin_amdgcn_mfma_f32_16x16x32_bf16(a, b, acc[nt], 0, 0, 0);
    }
  }
  int col = lane & 15;
  int rbase = r0 + (lane >> 4) * 4;
#pragma unroll
  for (int nt = 0; nt < 4; ++nt) {
    float b = bl[nt * 16 + col];
#pragma unroll
    for (int j = 0; j < 4; ++j) {
      int row = row0 + rbase + j;
      if (row < n) {
        float v = fmaxf(acc[nt][j] + b, 0.f);
        if (OUTBF) ((unsigned short*)outp)[(size_t)row * HD + nt * 16 + col] = f2bf(v);
        else       ((float*)outp)[(size_t)row * HD + nt * 16 + col] = v;
      }
    }
  }
}

// ---------------- SAGE linear via MFMA, K=96 (movie side, folded proj) -----

__global__ __launch_bounds__(256) void sage_um_kernel(
    const unsigned short* __restrict__ a24, const unsigned short* __restrict__ hm,
    const unsigned short* __restrict__ W96, const float* __restrict__ bl,
    unsigned short* __restrict__ m1, int n) {
  __shared__ unsigned short Xs[64][104];
  __shared__ unsigned short Ws[64][104];
  int t = threadIdx.x;
  int lane = t & 63, wid = t >> 6;
  int row0 = blockIdx.x * 64;
  int r0 = wid * 16;
  for (int i = t; i < 768; i += 256) {
    int h = i / 12, g = i - h * 12;
    *(uint4*)&Ws[h][g * 8] = *(const uint4*)(W96 + (size_t)h * 96 + g * 8);
  }
  for (int i = t; i < 768; i += 256) {
    int r = i / 12, g = i - r * 12;
    uint4 v = make_uint4(0u, 0u, 0u, 0u);
    if (row0 + r < n) {
      if (g < 4) v = *(const uint4*)(a24 + (size_t)(row0 + r) * 32 + g * 8);
      else       v = *(const uint4*)(hm + (size_t)(row0 + r) * HD + (g - 4) * 8);
    }
    *(uint4*)&Xs[r][g * 8] = v;
  }
  __syncthreads();
  f32x4 acc[4];
#pragma unroll
  for (int nt = 0; nt < 4; ++nt) acc[nt] = (f32x4){0.f, 0.f, 0.f, 0.f};
#pragma unroll
  for (int kk = 0; kk < 96; kk += 32) {
    bf16x8 a = *(const bf16x8*)&Xs[r0 + (lane & 15)][kk + (lane >> 4) * 8];
#pragma unroll
    for (int nt = 0; nt < 4; ++nt) {
      bf16x8 b = *(const bf16x8*)&Ws[nt * 16 + (lane & 15)][kk + (lane >> 4) * 8];
      acc[nt] = __builtin_amdgcn_mfma_f32_16x16x32_bf16(a, b, acc[nt], 0, 0, 0);
    }
  }
  int col = lane & 15;
  int rbase = r0 + (lane >> 4) * 4;
#pragma unroll
  for (int nt = 0; nt < 4; ++nt) {
    float b = bl[nt * 16 + col];
#pragma unroll
    for (int j = 0; j < 4; ++j) {
      int row = row0 + rbase + j;
      if (row < n)
        m1[(size_t)row * HD + nt * 16 + col] = f2bf(fmaxf(acc[nt][j] + b, 0.f));
    }
  }
}

// ---------------- layer 2 (z-trick) ----------------

__global__ __launch_bounds__(256) void zproj_kernel(
    const unsigned short* __restrict__ u1, const float* __restrict__ Wl2,
    float4* __restrict__ z) {
  __shared__ float W[3][64];
  int t = threadIdx.x;
  if (t < 192) W[t / 64][t & 63] = Wl2[t];
  __syncthreads();
  int wid = t >> 6, lane = t & 63;
  int g = lane >> 4, fq = lane & 15;
  int row = blockIdx.x * 16 + wid * 4 + g;
  if (row >= NU) return;
  uint2 v = *(const uint2*)(u1 + (size_t)row * HD + fq * 4);
  float2 p0 = unpk(v.x), p1 = unpk(v.y);
  int f = fq * 4;
  float z0 = p0.x * W[0][f] + p0.y * W[0][f + 1] + p1.x * W[0][f + 2] + p1.y * W[0][f + 3];
  float z1 = p0.x * W[1][f] + p0.y * W[1][f + 1] + p1.x * W[1][f + 2] + p1.y * W[1][f + 3];
  float z2 = p0.x * W[2][f] + p0.y * W[2][f + 1] + p1.x * W[2][f + 2] + p1.y * W[2][f + 3];
#pragma unroll
  for (int off = 1; off < 16; off <<= 1) {
    z0 += __shfl_xor(z0, off);
    z1 += __shfl_xor(z1, off);
    z2 += __shfl_xor(z2, off);
  }
  if (fq == 0) z[row] = make_float4(z0, z1, z2, 0.f);
}

__global__ __launch_bounds__(256) void agg4_kernel(
    const float4* __restrict__ z, const int* __restrict__ rp,
    const int* __restrict__ csr, float4* __restrict__ zagg, int n) {
  int wid = threadIdx.x >> 6, lane = threadIdx.x & 63;
  int row = blockIdx.x * 4 + wid;
  if (row >= n) return;
  int beg = rp[row], end = rp[row + 1];
  float s0 = 0.f, s1 = 0.f, s2 = 0.f;
  for (int i = beg + lane; i < end; i += 64) {
    float4 v = z[csr[i]];
    s0 += v.x; s1 += v.y; s2 += v.z;
  }
#pragma unroll
  for (int off = 1; off < 64; off <<= 1) {
    s0 += __shfl_xor(s0, off);
    s1 += __shfl_xor(s1, off);
    s2 += __shfl_xor(s2, off);
  }
  if (lane == 0) {
    float inv = 1.0f / fmaxf((float)(end - beg), 1.0f);
    zagg[row] = make_float4(s0 * inv, s1 * inv, s2 * inv, 0.f);
  }
}

__global__ void out2_kernel(const float4* __restrict__ zagg,
                            const unsigned short* __restrict__ m1,
                            const float* __restrict__ Wr2, const float* __restrict__ bl2,
                            float* __restrict__ out, int n) {
  int wid = threadIdx.x >> 6, lane = threadIdx.x & 63;
  int row = blockIdx.x * 4 + wid;
  if (row >= n) return;
  float mm = bf2f(m1[(size_t)row * HD + lane]);
  float4 za = zagg[row];
  float zc[3] = {za.x, za.y, za.z};
#pragma unroll
  for (int g = 0; g < 3; ++g) {
    float p = mm * Wr2[g * HD + lane];
#pragma unroll
    for (int off = 32; off > 0; off >>= 1) p += __shfl_down(p, off);
    if (lane == 0) out[row * 3 + g] = p + zc[g] + bl2[g];
  }
}

// ---------------------------------------------------------------------------

extern "C" void kernel_launch(void* const* d_in, const int* in_sizes, int n_in,
                              void* d_out, int out_size, void* d_ws, size_t ws_size,
                              hipStream_t stream) {
  const float* x_user  = (const float*)d_in[0];
  const float* x_movie = (const float*)d_in[1];
  const int*   e_src   = (const int*)d_in[2];
  const int*   e_dst   = (const int*)d_in[3];
  const float* W_user  = (const float*)d_in[4];
  const float* b_user  = (const float*)d_in[5];
  const float* W_movie = (const float*)d_in[6];
  const float* b_movie = (const float*)d_in[7];
  const float* Wl1_um  = (const float*)d_in[8];
  const float* bl1_um  = (const float*)d_in[9];
  const float* Wr1_um  = (const float*)d_in[10];
  const float* Wl1_mu  = (const float*)d_in[11];
  const float* bl1_mu  = (const float*)d_in[12];
  const float* Wr1_mu  = (const float*)d_in[13];
  const float* Wl2_um  = (const float*)d_in[14];
  const float* bl2_um  = (const float*)d_in[15];
  const float* Wr2_um  = (const float*)d_in[16];
  float* outp = (float*)d_out;

  // ---- workspace carve-up ----
  char* p = (char*)d_ws;
  size_t off = 0;
  auto take = [&](size_t bytes) { void* r = p + off; off += alignup(bytes); return r; };

  int* rp_m    = (int*)take(size_t(NM + 1) * 4);
  int* rp_u    = (int*)take(size_t(NU + 1) * 4);
  int* bh      = (int*)take(size_t(NBK) * 4);
  int* bbase_m = (int*)take(size_t(MBK + 1) * 4);
  int* bbase_u = (int*)take(size_t(UBK + 1) * 4);
  int* bcur_m  = (int*)take(size_t(MBK) * 4);
  int* bcur_u  = (int*)take(size_t(UBK) * 4);
  int* csr_m   = (int*)take(size_t(NE) * 4);
  int* csr_u   = (int*)take(size_t(NE) * 4);

  // overlay: staging (build phase) aliases feature buffers (feature phase)
  size_t ov_base = off;
  unsigned* stage_m = (unsigned*)take(size_t(NE) * 4);
  unsigned* stage_u = (unsigned*)take(size_t(NE) * 4);
  size_t stage_end = off;
  off = ov_base;
  unsigned short* hu   = (unsigned short*)take(size_t(NU) * HD * 2);
  unsigned short* hm   = (unsigned short*)take(size_t(NM) * HD * 2);
  unsigned short* u1   = (unsigned short*)take(size_t(NU) * HD * 2);
  unsigned short* m1   = (unsigned short*)take(size_t(NM) * HD * 2);
  unsigned short* aggb = (unsigned short*)take(size_t(NU) * HD * 2);
  unsigned char*  xu8  = (unsigned char*)take(size_t(NU) * 32);
  unsigned char*  hm8  = (unsigned char*)take(size_t(NM) * HD);
  unsigned short* a24  = (unsigned short*)take(size_t(NM) * 32 * 2);
  if (off < stage_end) off = stage_end;
  float4* z    = (float4*)take(size_t(NU) * 16);
  float4* zagg = (float4*)take(size_t(NM) * 16);
  unsigned short* Wb    = (unsigned short*)take(size_t(HD) * FM * 2);
  unsigned short* Wmu   = (unsigned short*)take(size_t(HD) * 128 * 2);
  unsigned short* Wum96 = (unsigned short*)take(size_t(HD) * 96 * 2);
  if (off > ws_size) return;

  const int TB = 256;

  // ---- CSR build ----
  hipMemsetAsync(bh, 0, size_t(NBK) * 4, stream);
  histB_kernel<<<512, 256, 0, stream>>>(e_src, e_dst, bh);
  scanB_kernel<<<1, 1024, 0, stream>>>(bh, bbase_m, bbase_u, bcur_m, bcur_u);
  passA_kernel<<<(NE + EPB - 1) / EPB, 1024, 0, stream>>>(e_src, e_dst, bcur_m, bcur_u,
                                                          stage_m, stage_u);
  passB_kernel<<<NBK, 1024, 0, stream>>>(bbase_m, bbase_u, stage_m, stage_u,
                                         csr_m, csr_u, rp_m, rp_u);

  // ---- projections + conversions ----
  convW_kernel<<<(HD * FM + 255) / 256, 256, 0, stream>>>(W_movie, Wb, HD * FM);
  convW2_kernel<<<(HD * 128 + 255) / 256, 256, 0, stream>>>(Wl1_mu, Wr1_mu, Wmu);
  convWum_kernel<<<(64 * 96 + 255) / 256, 256, 0, stream>>>(Wl1_um, W_user, b_user,
                                                            Wr1_um, Wum96);
  convXu_kernel<<<(NU * 32 + 255) / 256, 256, 0, stream>>>(x_user, xu8);
  proj_user_kernel<<<NU / 16, TB, 0, stream>>>(x_user, W_user, b_user, hu);
  proj_movie_kernel<<<(NM + 63) / 64, TB, 0, stream>>>(x_movie, Wb, b_movie, hm, hm8);

  // ---- layer 1: movie side ----
  agg24_kernel<<<(NM + 3) / 4, TB, 0, stream>>>(xu8, rp_m, csr_m, a24, NM);
  sage_um_kernel<<<(NM + 63) / 64, TB, 0, stream>>>(a24, hm, Wum96, bl1_um, m1, NM);

  // ---- layer 1: user side ----
  aggU_kernel<<<(NU + 3) / 4, TB, 0, stream>>>(hm8, rp_u, csr_u, aggb, NU);
  sage64_kernel<1><<<(NU + 63) / 64, TB, 0, stream>>>(aggb, hu, Wmu, bl1_mu, u1, NU);

  // ---- layer 2 (z-trick) ----
  zproj_kernel<<<(NU + 15) / 16, TB, 0, stream>>>(u1, Wl2_um, z);
  agg4_kernel<<<(NM + 3) / 4, TB, 0, stream>>>(z, rp_m, csr_m, zagg, NM);
  out2_kernel<<<(NM + 3) / 4, TB, 0, stream>>>(zagg, m1, Wr2_um, bl2_um, outp, NM);
}